// Round 4
// baseline (452.906 us; speedup 1.0000x reference)
//
#include <hip/hip_runtime.h>
#include <hip/hip_bf16.h>
#include <cstddef>

#define DIM 1024
#define NQ 16
#define NKV 4
#define HD 64
#define HID 2048
#define NE 8
#define SEQ 1024
#define EPSF 1e-6f
#define MAX_TILES 16   // 128-row tiles: max sum of ceil(cnt_e/128): 1024/128 + 8 = 16
#define GST 72         // LDS k-stride in bf16 elems: 144 B, 16B-aligned rows

typedef __hip_bfloat16 bf16;
typedef __attribute__((ext_vector_type(8))) short short8;   // 8 bf16 = one MFMA A/B frag
typedef __attribute__((ext_vector_type(4))) float floatx4;  // MFMA C/D frag

typedef union { short8 s; unsigned int u[4]; } s8u;

__device__ __forceinline__ unsigned int f2b(float f) {
    union { bf16 b; unsigned short s; } u;
    u.b = __float2bfloat16(f);
    return (unsigned int)u.s;
}
__device__ __forceinline__ unsigned int pk2(float a, float b) {
    return f2b(a) | (f2b(b) << 16);
}

// ---------------- RMSNorm (row of 1024, f32 in/out) ----------------
__global__ __launch_bounds__(256) void rmsnorm_kernel(const float* __restrict__ src,
                                                      const float* __restrict__ w,
                                                      float* __restrict__ dst)
{
    int row = blockIdx.x, tid = threadIdx.x;
    __shared__ float red[256];
    float vals[4];
    float sq = 0.f;
    size_t base = (size_t)row * DIM;
    #pragma unroll
    for (int i = 0; i < 4; i++) {
        int idx = tid + i * 256;
        float v = src[base + idx];
        vals[i] = v; sq += v * v;
    }
    red[tid] = sq; __syncthreads();
    for (int s = 128; s > 0; s >>= 1) {
        if (tid < s) red[tid] += red[tid + s];
        __syncthreads();
    }
    float rs = 1.0f / sqrtf(red[0] * (1.0f / DIM) + EPSF);
    #pragma unroll
    for (int i = 0; i < 4; i++) {
        int idx = tid + i * 256;
        dst[base + idx] = w[idx] * vals[i] * rs;
    }
}

// ---------------- MFMA bf16 tiled GEMM (64x64 tile, BK=64, 2-phase prefetch) ----
// Used for Wo (mode 1). Fragment layouts as verified (m89/m91).
__global__ __launch_bounds__(256) void gemm_kernel(
    const float* __restrict__ A, const float* __restrict__ B, const float* __restrict__ bias,
    float* __restrict__ C, const float* __restrict__ resf,
    int N, int K, int mode)
{
    __shared__ short As[64 * GST];
    __shared__ short Bs[64 * GST];
    int tid = threadIdx.x;
    int mbase = blockIdx.y * 64, nbase = blockIdx.x * 64;

    int ar = tid >> 4, ak = (tid & 15) << 2;
    int bn = tid & 63, bkk = (tid >> 6) << 4;
    const float* BpBase = B + (size_t)bkk * N + nbase + bn;

    int wv = tid >> 6, ln = tid & 63;
    int fm = (wv << 4) + (ln & 15);
    int fn = ln & 15;
    int fk = (ln >> 4) << 3;

    floatx4 acc[4];
    #pragma unroll
    for (int nt = 0; nt < 4; nt++)
        #pragma unroll
        for (int r = 0; r < 4; r++) acc[nt][r] = 0.f;

    float4 apre[4];
    float bpre[16];
    #pragma unroll
    for (int p = 0; p < 4; p++)
        apre[p] = *(const float4*)(A + (size_t)(mbase + (p << 4) + ar) * K + ak);
    #pragma unroll
    for (int i = 0; i < 16; i++)
        bpre[i] = BpBase[(size_t)i * N];

    for (int kt = 0; kt < K; kt += 64) {
        #pragma unroll
        for (int p = 0; p < 4; p++) {
            int m = (p << 4) + ar;
            uint2 wpk; wpk.x = pk2(apre[p].x, apre[p].y); wpk.y = pk2(apre[p].z, apre[p].w);
            *(uint2*)&As[m * GST + ak] = wpk;
        }
        {
            unsigned int u[8];
            #pragma unroll
            for (int i = 0; i < 8; i++) u[i] = pk2(bpre[2 * i], bpre[2 * i + 1]);
            *(uint4*)&Bs[bn * GST + bkk]     = make_uint4(u[0], u[1], u[2], u[3]);
            *(uint4*)&Bs[bn * GST + bkk + 8] = make_uint4(u[4], u[5], u[6], u[7]);
        }
        __syncthreads();

        int kn = kt + 64;
        if (kn < K) {
            #pragma unroll
            for (int p = 0; p < 4; p++)
                apre[p] = *(const float4*)(A + (size_t)(mbase + (p << 4) + ar) * K + kn + ak);
            const float* bp = BpBase + (size_t)kn * N;
            #pragma unroll
            for (int i = 0; i < 16; i++) bpre[i] = bp[(size_t)i * N];
        }

        #pragma unroll
        for (int ks = 0; ks < 2; ks++) {
            short8 af = *(const short8*)&As[fm * GST + (ks << 5) + fk];
            #pragma unroll
            for (int nt = 0; nt < 4; nt++) {
                short8 bf = *(const short8*)&Bs[((nt << 4) + fn) * GST + (ks << 5) + fk];
                acc[nt] = __builtin_amdgcn_mfma_f32_16x16x32_bf16(af, bf, acc[nt], 0, 0, 0);
            }
        }
        __syncthreads();
    }

    int rowb = mbase + (wv << 4) + ((ln >> 4) << 2);
    #pragma unroll
    for (int nt = 0; nt < 4; nt++) {
        int col = nbase + (nt << 4) + fn;
        float bsv = bias[col];
        #pragma unroll
        for (int r = 0; r < 4; r++) {
            float vv = acc[nt][r] + bsv;
            if (mode == 1) vv += resf[(size_t)(rowb + r) * N + col];
            C[(size_t)(rowb + r) * N + col] = vv;
        }
    }
}

// ---------------- MoE down-proj GEMM (128-row tile, mode-2 scatter) ----------------
// Two 64-row m-subtiles share one staged B-tile: 16 MFMA/wave per k-tile,
// half the W2 re-reads vs 64-row tiles.
__global__ __launch_bounds__(256) void gemm2_kernel(
    const float* __restrict__ A,        // act [MAX_TILES*128][HID]
    const float* __restrict__ W2,       // [E][HID][DIM]
    const float* __restrict__ b2,       // [E][DIM]
    float* __restrict__ C,              // out [SEQ][DIM]
    const float* __restrict__ resf,     // x2
    const int* __restrict__ perm,
    const int* __restrict__ tile_expert)
{
    __shared__ short As[128 * GST];
    __shared__ short Bs[64 * GST];
    int tid = threadIdx.x;
    int mbase = blockIdx.y * 128, nbase = blockIdx.x * 64;
    int e = tile_expert[blockIdx.y];
    if (e < 0) return;
    const int N = DIM, K = HID;
    const float* Bp = W2 + (size_t)e * K * N;
    const float* bias = b2 + (size_t)e * N;

    int ar = tid >> 4, ak = (tid & 15) << 2;
    int bn = tid & 63, bkk = (tid >> 6) << 4;
    const float* BpBase = Bp + (size_t)bkk * N + nbase + bn;

    int wv = tid >> 6, ln = tid & 63;
    int fm = (wv << 4) + (ln & 15);
    int fn = ln & 15;
    int fk = (ln >> 4) << 3;

    floatx4 acc[2][4];
    #pragma unroll
    for (int ms = 0; ms < 2; ms++)
        #pragma unroll
        for (int nt = 0; nt < 4; nt++)
            #pragma unroll
            for (int r = 0; r < 4; r++) acc[ms][nt][r] = 0.f;

    float4 apre[8];
    float bpre[16];
    #pragma unroll
    for (int p = 0; p < 8; p++)
        apre[p] = *(const float4*)(A + (size_t)(mbase + (p << 4) + ar) * K + ak);
    #pragma unroll
    for (int i = 0; i < 16; i++)
        bpre[i] = BpBase[(size_t)i * N];

    for (int kt = 0; kt < K; kt += 64) {
        #pragma unroll
        for (int p = 0; p < 8; p++) {
            int m = (p << 4) + ar;
            uint2 wpk; wpk.x = pk2(apre[p].x, apre[p].y); wpk.y = pk2(apre[p].z, apre[p].w);
            *(uint2*)&As[m * GST + ak] = wpk;
        }
        {
            unsigned int u[8];
            #pragma unroll
            for (int i = 0; i < 8; i++) u[i] = pk2(bpre[2 * i], bpre[2 * i + 1]);
            *(uint4*)&Bs[bn * GST + bkk]     = make_uint4(u[0], u[1], u[2], u[3]);
            *(uint4*)&Bs[bn * GST + bkk + 8] = make_uint4(u[4], u[5], u[6], u[7]);
        }
        __syncthreads();

        int kn = kt + 64;
        if (kn < K) {
            #pragma unroll
            for (int p = 0; p < 8; p++)
                apre[p] = *(const float4*)(A + (size_t)(mbase + (p << 4) + ar) * K + kn + ak);
            const float* bp = BpBase + (size_t)kn * N;
            #pragma unroll
            for (int i = 0; i < 16; i++) bpre[i] = bp[(size_t)i * N];
        }

        #pragma unroll
        for (int ks = 0; ks < 2; ks++) {
            short8 af0 = *(const short8*)&As[fm * GST + (ks << 5) + fk];
            short8 af1 = *(const short8*)&As[(fm + 64) * GST + (ks << 5) + fk];
            #pragma unroll
            for (int nt = 0; nt < 4; nt++) {
                short8 bf = *(const short8*)&Bs[((nt << 4) + fn) * GST + (ks << 5) + fk];
                acc[0][nt] = __builtin_amdgcn_mfma_f32_16x16x32_bf16(af0, bf, acc[0][nt], 0, 0, 0);
                acc[1][nt] = __builtin_amdgcn_mfma_f32_16x16x32_bf16(af1, bf, acc[1][nt], 0, 0, 0);
            }
        }
        __syncthreads();
    }

    #pragma unroll
    for (int ms = 0; ms < 2; ms++) {
        int rowb = mbase + (ms << 6) + (wv << 4) + ((ln >> 4) << 2);
        int tk[4];
        #pragma unroll
        for (int r = 0; r < 4; r++) tk[r] = perm[rowb + r];
        #pragma unroll
        for (int nt = 0; nt < 4; nt++) {
            int col = nbase + (nt << 4) + fn;
            float bsv = bias[col];
            #pragma unroll
            for (int r = 0; r < 4; r++)
                if (tk[r] >= 0)
                    C[(size_t)tk[r] * N + col] = resf[(size_t)tk[r] * N + col] + acc[ms][nt][r] + bsv;
        }
    }
}

// ---------------- Fused Q/K/V projection (one dispatch, per-block target select) ----
__global__ __launch_bounds__(256) void qkv_kernel(
    const float* __restrict__ A,
    const float* __restrict__ Wq, const float* __restrict__ bq,
    const float* __restrict__ Wk, const float* __restrict__ bk,
    const float* __restrict__ Wv, const float* __restrict__ bv,
    float* __restrict__ qo, float* __restrict__ ko, float* __restrict__ vo)
{
    __shared__ short As[64 * GST];
    __shared__ short Bs[64 * GST];
    int tid = threadIdx.x;
    int bx = blockIdx.x;
    int mbase = blockIdx.y * 64;

    const float* B; const float* bias; float* C; int N, nbase;
    if (bx < 16)      { B = Wq; bias = bq; C = qo; N = DIM;      nbase = bx * 64; }
    else if (bx < 20) { B = Wk; bias = bk; C = ko; N = NKV * HD; nbase = (bx - 16) * 64; }
    else              { B = Wv; bias = bv; C = vo; N = NKV * HD; nbase = (bx - 20) * 64; }

    int ar = tid >> 4, ak = (tid & 15) << 2;
    int bn = tid & 63, bkk = (tid >> 6) << 4;
    const float* BpBase = B + (size_t)bkk * N + nbase + bn;

    int wv = tid >> 6, ln = tid & 63;
    int fm = (wv << 4) + (ln & 15);
    int fn = ln & 15;
    int fk = (ln >> 4) << 3;

    floatx4 acc[4];
    #pragma unroll
    for (int nt = 0; nt < 4; nt++)
        #pragma unroll
        for (int r = 0; r < 4; r++) acc[nt][r] = 0.f;

    float4 apre[4];
    float bpre[16];
    #pragma unroll
    for (int p = 0; p < 4; p++)
        apre[p] = *(const float4*)(A + (size_t)(mbase + (p << 4) + ar) * DIM + ak);
    #pragma unroll
    for (int i = 0; i < 16; i++)
        bpre[i] = BpBase[(size_t)i * N];

    for (int kt = 0; kt < DIM; kt += 64) {
        #pragma unroll
        for (int p = 0; p < 4; p++) {
            int m = (p << 4) + ar;
            uint2 wpk; wpk.x = pk2(apre[p].x, apre[p].y); wpk.y = pk2(apre[p].z, apre[p].w);
            *(uint2*)&As[m * GST + ak] = wpk;
        }
        {
            unsigned int u[8];
            #pragma unroll
            for (int i = 0; i < 8; i++) u[i] = pk2(bpre[2 * i], bpre[2 * i + 1]);
            *(uint4*)&Bs[bn * GST + bkk]     = make_uint4(u[0], u[1], u[2], u[3]);
            *(uint4*)&Bs[bn * GST + bkk + 8] = make_uint4(u[4], u[5], u[6], u[7]);
        }
        __syncthreads();

        int kn = kt + 64;
        if (kn < DIM) {
            #pragma unroll
            for (int p = 0; p < 4; p++)
                apre[p] = *(const float4*)(A + (size_t)(mbase + (p << 4) + ar) * DIM + kn + ak);
            const float* bp = BpBase + (size_t)kn * N;
            #pragma unroll
            for (int i = 0; i < 16; i++) bpre[i] = bp[(size_t)i * N];
        }

        #pragma unroll
        for (int ks = 0; ks < 2; ks++) {
            short8 af = *(const short8*)&As[fm * GST + (ks << 5) + fk];
            #pragma unroll
            for (int nt = 0; nt < 4; nt++) {
                short8 bf = *(const short8*)&Bs[((nt << 4) + fn) * GST + (ks << 5) + fk];
                acc[nt] = __builtin_amdgcn_mfma_f32_16x16x32_bf16(af, bf, acc[nt], 0, 0, 0);
            }
        }
        __syncthreads();
    }

    int rowb = mbase + (wv << 4) + ((ln >> 4) << 2);
    #pragma unroll
    for (int nt = 0; nt < 4; nt++) {
        int col = nbase + (nt << 4) + fn;
        float bsv = bias[col];
        #pragma unroll
        for (int r = 0; r < 4; r++)
            C[(size_t)(rowb + r) * N + col] = acc[nt][r] + bsv;
    }
}

// ---------------- Fused MoE up-proj + SwiGLU (128-row tile, dual-B, prefetch) -----
__global__ __launch_bounds__(256) void moe1_kernel(
    const float* __restrict__ A,        // h2 [SEQ][DIM]
    const float* __restrict__ W1,       // [E][DIM][2*HID]
    const float* __restrict__ b1,       // [E][2*HID]
    float* __restrict__ act,            // [MAX_TILES*128][HID]
    const int* __restrict__ perm,
    const int* __restrict__ tile_expert)
{
    __shared__ short As[128 * GST];
    __shared__ short B1s[64 * GST];
    __shared__ short B2s[64 * GST];
    int tid = threadIdx.x;
    int mbase = blockIdx.y * 128, nbase = blockIdx.x * 64;
    int e = tile_expert[blockIdx.y];
    if (e < 0) return;
    const float* Wp = W1 + (size_t)e * DIM * (2 * HID);
    const float* bp1 = b1 + (size_t)e * (2 * HID);

    int ar = tid >> 4, ak = (tid & 15) << 2;
    int tok[8];
    #pragma unroll
    for (int p = 0; p < 8; p++) tok[p] = perm[mbase + (p << 4) + ar];

    int bn = tid & 63, bkk = (tid >> 6) << 4;
    const float* BpBase = Wp + (size_t)bkk * (2 * HID) + nbase + bn;

    int wv = tid >> 6, ln = tid & 63;
    int fm = (wv << 4) + (ln & 15);
    int fn = ln & 15;
    int fk = (ln >> 4) << 3;

    floatx4 acc1[2][4], acc2[2][4];
    #pragma unroll
    for (int ms = 0; ms < 2; ms++)
        #pragma unroll
        for (int nt = 0; nt < 4; nt++)
            #pragma unroll
            for (int r = 0; r < 4; r++) { acc1[ms][nt][r] = 0.f; acc2[ms][nt][r] = 0.f; }

    float4 apre[8];
    float b1pre[16], b2pre[16];
    #pragma unroll
    for (int p = 0; p < 8; p++)
        apre[p] = (tok[p] >= 0)
            ? *(const float4*)(A + (size_t)tok[p] * DIM + ak)
            : make_float4(0.f, 0.f, 0.f, 0.f);
    #pragma unroll
    for (int i = 0; i < 16; i++) {
        b1pre[i] = BpBase[(size_t)i * (2 * HID)];
        b2pre[i] = BpBase[(size_t)i * (2 * HID) + HID];
    }

    for (int kt = 0; kt < DIM; kt += 64) {
        #pragma unroll
        for (int p = 0; p < 8; p++) {
            int m = (p << 4) + ar;
            uint2 wpk; wpk.x = pk2(apre[p].x, apre[p].y); wpk.y = pk2(apre[p].z, apre[p].w);
            *(uint2*)&As[m * GST + ak] = wpk;
        }
        {
            unsigned int u1[8], u2[8];
            #pragma unroll
            for (int i = 0; i < 8; i++) {
                u1[i] = pk2(b1pre[2 * i], b1pre[2 * i + 1]);
                u2[i] = pk2(b2pre[2 * i], b2pre[2 * i + 1]);
            }
            *(uint4*)&B1s[bn * GST + bkk]     = make_uint4(u1[0], u1[1], u1[2], u1[3]);
            *(uint4*)&B1s[bn * GST + bkk + 8] = make_uint4(u1[4], u1[5], u1[6], u1[7]);
            *(uint4*)&B2s[bn * GST + bkk]     = make_uint4(u2[0], u2[1], u2[2], u2[3]);
            *(uint4*)&B2s[bn * GST + bkk + 8] = make_uint4(u2[4], u2[5], u2[6], u2[7]);
        }
        __syncthreads();

        int kn = kt + 64;
        if (kn < DIM) {
            #pragma unroll
            for (int p = 0; p < 8; p++)
                apre[p] = (tok[p] >= 0)
                    ? *(const float4*)(A + (size_t)tok[p] * DIM + kn + ak)
                    : make_float4(0.f, 0.f, 0.f, 0.f);
            const float* bp = BpBase + (size_t)kn * (2 * HID);
            #pragma unroll
            for (int i = 0; i < 16; i++) {
                b1pre[i] = bp[(size_t)i * (2 * HID)];
                b2pre[i] = bp[(size_t)i * (2 * HID) + HID];
            }
        }

        #pragma unroll
        for (int ks = 0; ks < 2; ks++) {
            short8 af0 = *(const short8*)&As[fm * GST + (ks << 5) + fk];
            short8 af1 = *(const short8*)&As[(fm + 64) * GST + (ks << 5) + fk];
            #pragma unroll
            for (int nt = 0; nt < 4; nt++) {
                int bo = ((nt << 4) + fn) * GST + (ks << 5) + fk;
                short8 bf1 = *(const short8*)&B1s[bo];
                short8 bf2 = *(const short8*)&B2s[bo];
                acc1[0][nt] = __builtin_amdgcn_mfma_f32_16x16x32_bf16(af0, bf1, acc1[0][nt], 0, 0, 0);
                acc1[1][nt] = __builtin_amdgcn_mfma_f32_16x16x32_bf16(af1, bf1, acc1[1][nt], 0, 0, 0);
                acc2[0][nt] = __builtin_amdgcn_mfma_f32_16x16x32_bf16(af0, bf2, acc2[0][nt], 0, 0, 0);
                acc2[1][nt] = __builtin_amdgcn_mfma_f32_16x16x32_bf16(af1, bf2, acc2[1][nt], 0, 0, 0);
            }
        }
        __syncthreads();
    }

    #pragma unroll
    for (int ms = 0; ms < 2; ms++) {
        int rowb = mbase + (ms << 6) + (wv << 4) + ((ln >> 4) << 2);
        #pragma unroll
        for (int nt = 0; nt < 4; nt++) {
            int col = nbase + (nt << 4) + fn;
            float bs1 = bp1[col];
            float bs2 = bp1[HID + col];
            #pragma unroll
            for (int r = 0; r < 4; r++) {
                float u1 = acc1[ms][nt][r] + bs1;
                float u2 = acc2[ms][nt][r] + bs2;
                act[(size_t)(rowb + r) * HID + col] = u1 * (1.0f / (1.0f + expf(-u2)));
            }
        }
    }
}

// ---------------- RoPE + per-head RMSNorm (merged q/k dispatch) ----------------
// blockIdx.y < NQ: q head; else k head (blockIdx.y - NQ).
__global__ __launch_bounds__(64) void rope_rms_kernel(float* __restrict__ qb,
                                                      float* __restrict__ kb,
                                                      const float* __restrict__ qnw,
                                                      const float* __restrict__ knw)
{
    int t = blockIdx.x, hy = blockIdx.y, d = threadIdx.x;
    float* x; const float* w; int nh, h;
    if (hy < NQ) { x = qb; w = qnw; nh = NQ;  h = hy; }
    else         { x = kb; w = knw; nh = NKV; h = hy - NQ; }
    int base = (t * nh + h) * HD;
    int i = d & 31;
    float x1 = x[base + i];
    float x2 = x[base + 32 + i];
    float inv = 1.0f / powf(10000.0f, (float)(2 * i) * (1.0f / HD));
    float fr = (float)t * inv;
    float c = cosf(fr), s = sinf(fr);
    float r = (d < 32) ? (x1 * c - x2 * s) : (x1 * s + x2 * c);
    float sq = r * r;
    #pragma unroll
    for (int m = 32; m >= 1; m >>= 1) sq += __shfl_xor(sq, m);
    float rs = 1.0f / sqrtf(sq * (1.0f / HD) + EPSF);
    __syncthreads();
    x[base + d] = r * rs * w[d];
}

// ---------------- MFMA flash attention (causal GQA) + fused sigmoid gate --------
__global__ __launch_bounds__(256) void fattn_kernel(const float* __restrict__ q,
                                                    const float* __restrict__ k,
                                                    const float* __restrict__ v,
                                                    const float* __restrict__ Wg,
                                                    const float* __restrict__ bg,
                                                    float* __restrict__ o)
{
    __shared__ short lds[2][2][64 * GST];   // [buf][0=K,1=V^T] ; 36864 B

    int h = blockIdx.x, qt = blockIdx.y;
    int kvh = h >> 2;
    int tid = threadIdx.x;
    int w = tid >> 6, ln = tid & 63;
    int c = ln & 15, g = ln >> 4;
    int qbase = qt * 64;
    const size_t krow = (size_t)NKV * HD;   // floats per token row in k/v

    short8 qf[2];
    {
        const float* qp = q + ((size_t)(qbase + 16 * w + c) * NQ + h) * HD + 8 * g;
        #pragma unroll
        for (int ks = 0; ks < 2; ks++) {
            float4 a = *(const float4*)(qp + 32 * ks);
            float4 b = *(const float4*)(qp + 32 * ks + 4);
            s8u t;
            t.u[0] = pk2(a.x * 0.125f, a.y * 0.125f);
            t.u[1] = pk2(a.z * 0.125f, a.w * 0.125f);
            t.u[2] = pk2(b.x * 0.125f, b.y * 0.125f);
            t.u[3] = pk2(b.z * 0.125f, b.w * 0.125f);
            qf[ks] = t.s;
        }
    }

    int kr[4], kd4[4];
    #pragma unroll
    for (int i = 0; i < 4; i++) { int f4 = tid + 256 * i; kr[i] = f4 >> 4; kd4[i] = f4 & 15; }
    int vd = tid & 63, vrb = (tid >> 6) << 4;

    float4 kreg[4];
    float vreg[16];
    {
        const float* kb = k + (size_t)kvh * HD;
        #pragma unroll
        for (int i = 0; i < 4; i++)
            kreg[i] = *(const float4*)(kb + (size_t)kr[i] * krow + kd4[i] * 4);
        const float* vb = v + (size_t)kvh * HD + vd;
        #pragma unroll
        for (int i = 0; i < 16; i++)
            vreg[i] = vb[(size_t)(vrb + i) * krow];
    }

    float m_i = -INFINITY, l_i = 0.f;
    floatx4 ot[4];
    #pragma unroll
    for (int mt = 0; mt < 4; mt++)
        #pragma unroll
        for (int r = 0; r < 4; r++) ot[mt][r] = 0.f;

    for (int kt = 0; kt <= qt; kt++) {
        short* KB = lds[kt & 1][0];
        short* VT = lds[kt & 1][1];

        #pragma unroll
        for (int i = 0; i < 4; i++) {
            uint2 wp; wp.x = pk2(kreg[i].x, kreg[i].y); wp.y = pk2(kreg[i].z, kreg[i].w);
            *(uint2*)&KB[kr[i] * GST + kd4[i] * 4] = wp;
        }
        {
            unsigned int u[8];
            #pragma unroll
            for (int i = 0; i < 8; i++) u[i] = pk2(vreg[2 * i], vreg[2 * i + 1]);
            *(uint4*)&VT[vd * GST + vrb]     = make_uint4(u[0], u[1], u[2], u[3]);
            *(uint4*)&VT[vd * GST + vrb + 8] = make_uint4(u[4], u[5], u[6], u[7]);
        }
        __syncthreads();

        if (kt < qt) {
            int kb2 = (kt + 1) * 64;
            const float* kb = k + ((size_t)kb2 * NKV + kvh) * HD;
            #pragma unroll
            for (int i = 0; i < 4; i++)
                kreg[i] = *(const float4*)(kb + (size_t)kr[i] * krow + kd4[i] * 4);
            const float* vp = v + ((size_t)kb2 * NKV + kvh) * HD + vd;
            #pragma unroll
            for (int i = 0; i < 16; i++)
                vreg[i] = vp[(size_t)(vrb + i) * krow];
        }

        float p[4][4];
        #pragma unroll
        for (int mt = 0; mt < 4; mt++) {
            floatx4 s = {0.f, 0.f, 0.f, 0.f};
            #pragma unroll
            for (int ks = 0; ks < 2; ks++) {
                short8 kf = *(const short8*)&KB[(16 * mt + c) * GST + 32 * ks + 8 * g];
                s = __builtin_amdgcn_mfma_f32_16x16x32_bf16(kf, qf[ks], s, 0, 0, 0);
            }
            #pragma unroll
            for (int r = 0; r < 4; r++) p[mt][r] = s[r];
        }

        if (kt == qt) {
            #pragma unroll
            for (int mt = 0; mt < 4; mt++)
                #pragma unroll
                for (int r = 0; r < 4; r++)
                    if (16 * mt + 4 * g + r > 16 * w + c) p[mt][r] = -1e30f;
        }

        float tm = p[0][0];
        #pragma unroll
        for (int mt = 0; mt < 4; mt++)
            #pragma unroll
            for (int r = 0; r < 4; r++) tm = fmaxf(tm, p[mt][r]);
        tm = fmaxf(tm, __shfl_xor(tm, 16));
        tm = fmaxf(tm, __shfl_xor(tm, 32));
        float mn = fmaxf(m_i, tm);
        float alpha = __expf(m_i - mn);
        float ts = 0.f;
        #pragma unroll
        for (int mt = 0; mt < 4; mt++)
            #pragma unroll
            for (int r = 0; r < 4; r++) {
                float e = __expf(p[mt][r] - mn);
                p[mt][r] = e; ts += e;
            }
        ts += __shfl_xor(ts, 16);
        ts += __shfl_xor(ts, 32);
        l_i = alpha * l_i + ts;
        m_i = mn;
        #pragma unroll
        for (int mt = 0; mt < 4; mt++)
            #pragma unroll
            for (int r = 0; r < 4; r++) ot[mt][r] *= alpha;

        unsigned int pd[4][2];
        #pragma unroll
        for (int mt = 0; mt < 4; mt++) {
            pd[mt][0] = pk2(p[mt][0], p[mt][1]);
            pd[mt][1] = pk2(p[mt][2], p[mt][3]);
        }

        int srcA = c + ((ln & 16) << 1);
        int srcB = srcA + 16;
        int gh = g >> 1;
        short8 pf[2];
        #pragma unroll
        for (int ks = 0; ks < 2; ks++) {
            s8u t;
            unsigned int a0 = (unsigned)__shfl((int)pd[2 * ks][0],     srcA);
            unsigned int a1 = (unsigned)__shfl((int)pd[2 * ks + 1][0], srcA);
            t.u[0] = gh ? a1 : a0;
            unsigned int b0 = (unsigned)__shfl((int)pd[2 * ks][1],     srcA);
            unsigned int b1 = (unsigned)__shfl((int)pd[2 * ks + 1][1], srcA);
            t.u[1] = gh ? b1 : b0;
            unsigned int c0 = (unsigned)__shfl((int)pd[2 * ks][0],     srcB);
            unsigned int c1 = (unsigned)__shfl((int)pd[2 * ks + 1][0], srcB);
            t.u[2] = gh ? c1 : c0;
            unsigned int d0 = (unsigned)__shfl((int)pd[2 * ks][1],     srcB);
            unsigned int d1 = (unsigned)__shfl((int)pd[2 * ks + 1][1], srcB);
            t.u[3] = gh ? d1 : d0;
            pf[ks] = t.s;
        }

        #pragma unroll
        for (int mt = 0; mt < 4; mt++) {
            #pragma unroll
            for (int ks = 0; ks < 2; ks++) {
                short8 vf = *(const short8*)&VT[(16 * mt + c) * GST + 32 * ks + 8 * g];
                ot[mt] = __builtin_amdgcn_mfma_f32_16x16x32_bf16(vf, pf[ks], ot[mt], 0, 0, 0);
            }
        }
    }

    // ---- epilogue: normalize -> OT LDS; stage Wg; fused f32 gate; store --------
    __syncthreads();
    float* L   = (float*)lds;          // OT [64][68] f32 = 17408 B
    float* WgS = L + 64 * 68;          // Wg [64][68] f32 = 17408 B (total 34816 B)

    // issue Wg global loads early (land during OT writes)
    int we = tid >> 2, wd = (tid & 3) << 4;
    float4 wg4[4];
    #pragma unroll
    for (int i = 0; i < 4; i++)
        wg4[i] = *(const float4*)(Wg + (size_t)we * HD + wd + 4 * i);

    float rl = 1.0f / l_i;
    #pragma unroll
    for (int mt = 0; mt < 4; mt++)
        #pragma unroll
        for (int r = 0; r < 4; r++)
            L[(16 * w + c) * 68 + 16 * mt + 4 * g + r] = ot[mt][r] * rl;
    #pragma unroll
    for (int i = 0; i < 4; i++)
        *(float4*)&WgS[we * 68 + wd + 4 * i] = wg4[i];
    __syncthreads();

    // gate: row r = tid>>2, cols d0..d0+15; f32, same order as old gate_kernel
    int r = tid >> 2, d0 = (tid & 3) << 4;
    float4 a0 = *(const float4*)(bg + d0);
    float4 a1 = *(const float4*)(bg + d0 + 4);
    float4 a2 = *(const float4*)(bg + d0 + 8);
    float4 a3 = *(const float4*)(bg + d0 + 12);
    for (int e = 0; e < HD; e++) {
        float ov = L[r * 68 + e];
        float4 w0 = *(const float4*)&WgS[e * 68 + d0];
        float4 w1 = *(const float4*)&WgS[e * 68 + d0 + 4];
        float4 w2 = *(const float4*)&WgS[e * 68 + d0 + 8];
        float4 w3 = *(const float4*)&WgS[e * 68 + d0 + 12];
        a0.x += ov * w0.x; a0.y += ov * w0.y; a0.z += ov * w0.z; a0.w += ov * w0.w;
        a1.x += ov * w1.x; a1.y += ov * w1.y; a1.z += ov * w1.z; a1.w += ov * w1.w;
        a2.x += ov * w2.x; a2.y += ov * w2.y; a2.z += ov * w2.z; a2.w += ov * w2.w;
        a3.x += ov * w3.x; a3.y += ov * w3.y; a3.z += ov * w3.z; a3.w += ov * w3.w;
    }
    float* op = o + ((size_t)(qbase + r) * NQ + h) * HD + d0;
    float4 res[4];
    float4 av[4] = {a0, a1, a2, a3};
    #pragma unroll
    for (int i = 0; i < 4; i++) {
        float4 ov4 = *(const float4*)&L[r * 68 + d0 + 4 * i];
        res[i].x = ov4.x / (1.0f + expf(-av[i].x));
        res[i].y = ov4.y / (1.0f + expf(-av[i].y));
        res[i].z = ov4.z / (1.0f + expf(-av[i].z));
        res[i].w = ov4.w / (1.0f + expf(-av[i].w));
        *(float4*)(op + 4 * i) = res[i];
    }
}

// ---------------- Router: logits + argmax (one wave per token) ----------------
__global__ __launch_bounds__(64) void router_kernel(const float* __restrict__ h2,
                                                    const float* __restrict__ Wr,
                                                    const float* __restrict__ br,
                                                    int* __restrict__ top1)
{
    int t = blockIdx.x, lane = threadIdx.x;
    float acc[NE] = {0.f, 0.f, 0.f, 0.f, 0.f, 0.f, 0.f, 0.f};
    for (int d = lane; d < DIM; d += 64) {
        float hv = h2[(size_t)t * DIM + d];
        float4 w0 = *(const float4*)(Wr + (size_t)d * NE);
        float4 w1 = *(const float4*)(Wr + (size_t)d * NE + 4);
        acc[0] += hv * w0.x; acc[1] += hv * w0.y;
        acc[2] += hv * w0.z; acc[3] += hv * w0.w;
        acc[4] += hv * w1.x; acc[5] += hv * w1.y;
        acc[6] += hv * w1.z; acc[7] += hv * w1.w;
    }
    #pragma unroll
    for (int e = 0; e < NE; e++)
        for (int off = 32; off >= 1; off >>= 1) acc[e] += __shfl_down(acc[e], off);
    if (lane == 0) {
        float best = acc[0] + br[0]; int be = 0;
        #pragma unroll
        for (int e = 1; e < NE; e++) {
            float l = acc[e] + br[e];
            if (l > best) { best = l; be = e; }   // strict > : first max wins (np.argmax)
        }
        top1[t] = be;
    }
}

// ---------------- Bucket tokens by expert into 128-padded tiles ----------------
__global__ __launch_bounds__(64) void bucket_kernel(const int* __restrict__ top1,
                                                    int* __restrict__ perm,
                                                    int* __restrict__ tile_expert)
{
    int lane = threadIdx.x;

    int e_of[16];
    {
        const int4* tp = (const int4*)(top1 + lane * 16);
        #pragma unroll
        for (int c = 0; c < 4; c++) {
            int4 v = tp[c];
            e_of[c * 4 + 0] = v.x & 7;
            e_of[c * 4 + 1] = v.y & 7;
            e_of[c * 4 + 2] = v.z & 7;
            e_of[c * 4 + 3] = v.w & 7;
        }
    }

    int cnt[NE];
    #pragma unroll
    for (int e = 0; e < NE; e++) {
        int c = 0;
        #pragma unroll
        for (int i = 0; i < 16; i++) c += (e_of[i] == e) ? 1 : 0;
        cnt[e] = c;
    }

    int pre[NE];
    #pragma unroll
    for (int e = 0; e < NE; e++) pre[e] = cnt[e];
    #pragma unroll
    for (int off = 1; off < 64; off <<= 1) {
        #pragma unroll
        for (int e = 0; e < NE; e++) {
            int t = __shfl_up(pre[e], off);
            if (lane >= off) pre[e] += t;
        }
    }
    int tot[NE];
    #pragma unroll
    for (int e = 0; e < NE; e++) {
        tot[e] = __shfl(pre[e], 63);
        pre[e] -= cnt[e];
    }

    // 128-padded tile offsets
    int off_e[NE + 1];
    off_e[0] = 0;
    #pragma unroll
    for (int e = 0; e < NE; e++)
        off_e[e + 1] = off_e[e] + (((tot[e] + 127) >> 7) << 7);

    if (lane < MAX_TILES) {
        int tb = lane << 7;
        int te = -1;
        #pragma unroll
        for (int e = 0; e < NE; e++)
            if (tb >= off_e[e] && tb < off_e[e + 1]) te = e;
        tile_expert[lane] = te;
    }

    #pragma unroll
    for (int e = 0; e < NE; e++)
        for (int i = off_e[e] + tot[e] + lane; i < off_e[e + 1]; i += 64)
            perm[i] = -1;

    #pragma unroll
    for (int e = 0; e < NE; e++) {
        int pos = off_e[e] + pre[e];
        #pragma unroll
        for (int i = 0; i < 16; i++) {
            if (e_of[i] == e) { perm[pos] = lane * 16 + i; pos++; }
        }
    }
}

extern "C" void kernel_launch(void* const* d_in, const int* in_sizes, int n_in,
                              void* d_out, int out_size, void* d_ws, size_t ws_size,
                              hipStream_t stream)
{
    const float* x    = (const float*)d_in[0];
    const float* ln1w = (const float*)d_in[1];
    const float* ln2w = (const float*)d_in[2];
    const float* Wq   = (const float*)d_in[3];
    const float* bq   = (const float*)d_in[4];
    const float* Wk   = (const float*)d_in[5];
    const float* bk   = (const float*)d_in[6];
    const float* Wv   = (const float*)d_in[7];
    const float* bv   = (const float*)d_in[8];
    const float* qnw  = (const float*)d_in[9];
    const float* knw  = (const float*)d_in[10];
    const float* Wg   = (const float*)d_in[11];
    const float* bg   = (const float*)d_in[12];
    const float* Wo   = (const float*)d_in[13];
    const float* bo   = (const float*)d_in[14];
    const float* Wr   = (const float*)d_in[15];
    const float* br   = (const float*)d_in[16];
    const float* W1   = (const float*)d_in[17];
    const float* b1   = (const float*)d_in[18];
    const float* W2   = (const float*)d_in[19];
    const float* b2   = (const float*)d_in[20];
    float* out = (float*)d_out;
    (void)in_sizes; (void)n_in; (void)out_size; (void)ws_size;

    char* ws = (char*)d_ws;
    float* h    = (float*)(ws);
    float* q    = (float*)(ws + ((size_t)4  << 20));
    float* kbuf = (float*)(ws + ((size_t)8  << 20));
    float* vbuf = (float*)(ws + ((size_t)9  << 20));
    float* ao   = (float*)(ws + ((size_t)10 << 20));
    float* x2   = (float*)(ws);                          // over h (dead)
    float* h2   = (float*)(ws + ((size_t)4  << 20));     // over q (dead)
    float* act  = (float*)(ws + ((size_t)24 << 20));     // 16 MB: [16*128][HID]
    int* top1   = (int*)  (ws + ((size_t)44 << 20));
    int* perm   = top1 + 2048;
    int* texp   = perm + MAX_TILES * 128;

    rmsnorm_kernel<<<SEQ, 256, 0, stream>>>(x, ln1w, h);
    qkv_kernel<<<dim3(24, SEQ / 64), 256, 0, stream>>>(
        h, Wq, bq, Wk, bk, Wv, bv, q, kbuf, vbuf);
    rope_rms_kernel<<<dim3(SEQ, NQ + NKV), 64, 0, stream>>>(q, kbuf, qnw, knw);
    fattn_kernel<<<dim3(NQ, SEQ / 64), 256, 0, stream>>>(q, kbuf, vbuf, Wg, bg, ao);
    gemm_kernel<<<dim3(DIM / 64, SEQ / 64), 256, 0, stream>>>(
        ao, Wo, bo, x2, x, DIM, DIM, 1);
    rmsnorm_kernel<<<SEQ, 256, 0, stream>>>(x2, ln2w, h2);
    router_kernel<<<SEQ, 64, 0, stream>>>(h2, Wr, br, top1);
    bucket_kernel<<<1, 64, 0, stream>>>(top1, perm, texp);
    moe1_kernel<<<dim3(HID / 64, MAX_TILES), 256, 0, stream>>>(
        h2, W1, b1, act, perm, texp);
    gemm2_kernel<<<dim3(DIM / 64, MAX_TILES), 256, 0, stream>>>(
        act, W2, b2, out, x2, perm, texp);
}

// Round 5
// 450.343 us; speedup vs baseline: 1.0057x; 1.0057x over previous
//
#include <hip/hip_runtime.h>
#include <hip/hip_bf16.h>
#include <cstddef>

#define DIM 1024
#define NQ 16
#define NKV 4
#define HD 64
#define HID 2048
#define NE 8
#define SEQ 1024
#define EPSF 1e-6f
#define MAX_TILES 24   // 64-row tiles: max sum of ceil(cnt_e/64): 1024/64 + 8 = 24
#define GST 72         // LDS k-stride in bf16 elems: 144 B, 16B-aligned rows

typedef __hip_bfloat16 bf16;
typedef __attribute__((ext_vector_type(8))) short short8;   // 8 bf16 = one MFMA A/B frag
typedef __attribute__((ext_vector_type(4))) float floatx4;  // MFMA C/D frag

typedef union { short8 s; unsigned int u[4]; } s8u;

__device__ __forceinline__ unsigned int f2b(float f) {
    union { bf16 b; unsigned short s; } u;
    u.b = __float2bfloat16(f);
    return (unsigned int)u.s;
}
__device__ __forceinline__ unsigned int pk2(float a, float b) {
    return f2b(a) | (f2b(b) << 16);
}

// ---------------- RMSNorm (row of 1024, f32 in/out) ----------------
__global__ __launch_bounds__(256) void rmsnorm_kernel(const float* __restrict__ src,
                                                      const float* __restrict__ w,
                                                      float* __restrict__ dst)
{
    int row = blockIdx.x, tid = threadIdx.x;
    __shared__ float red[256];
    float vals[4];
    float sq = 0.f;
    size_t base = (size_t)row * DIM;
    #pragma unroll
    for (int i = 0; i < 4; i++) {
        int idx = tid + i * 256;
        float v = src[base + idx];
        vals[i] = v; sq += v * v;
    }
    red[tid] = sq; __syncthreads();
    for (int s = 128; s > 0; s >>= 1) {
        if (tid < s) red[tid] += red[tid + s];
        __syncthreads();
    }
    float rs = 1.0f / sqrtf(red[0] * (1.0f / DIM) + EPSF);
    #pragma unroll
    for (int i = 0; i < 4; i++) {
        int idx = tid + i * 256;
        dst[base + idx] = w[idx] * vals[i] * rs;
    }
}

// ---------------- MFMA bf16 tiled GEMM (64x64 tile, BK=64) ----------------
// Depth-2 pipeline, LDS double-buffer, ONE barrier per k-tile (pairwise
// hand-unrolled so all buffer indices are compile-time; K/64 must be even).
// mode 0: C = acc + bias ; mode 1: += resf[row] ; mode 2: perm-scatter + resf[tok]
__global__ __launch_bounds__(256) void gemm_kernel(
    const float* __restrict__ A, const float* __restrict__ B, const float* __restrict__ bias,
    float* __restrict__ C, const float* __restrict__ resf,
    const int* __restrict__ perm, const int* __restrict__ tile_expert,
    int N, int K, int mode)
{
    __shared__ short As[2][64 * GST];
    __shared__ short Bs[2][64 * GST];
    int tid = threadIdx.x;
    int mbase = blockIdx.y * 64, nbase = blockIdx.x * 64;

    size_t Beoff = 0, biasoff = 0;
    if (tile_expert) {
        int e = tile_expert[blockIdx.y];
        if (e < 0) return;
        Beoff = (size_t)e * K * N;
        biasoff = (size_t)e * N;
    }

    int ar = tid >> 4, ak = (tid & 15) << 2;
    int bn = tid & 63, bkk = (tid >> 6) << 4;
    const float* BpBase = B + Beoff + (size_t)bkk * N + nbase + bn;

    int wv = tid >> 6, ln = tid & 63;
    int fm = (wv << 4) + (ln & 15);
    int fn = ln & 15;
    int fk = (ln >> 4) << 3;

    floatx4 acc[4];
    #pragma unroll
    for (int nt = 0; nt < 4; nt++)
        #pragma unroll
        for (int r = 0; r < 4; r++) acc[nt][r] = 0.f;

    float4 aA[4], aB[4];
    float bA[16], bB[16];

    auto LOAD = [&](int kt2, float4* ap, float* bp_) {
        #pragma unroll
        for (int p = 0; p < 4; p++)
            ap[p] = *(const float4*)(A + (size_t)(mbase + (p << 4) + ar) * K + kt2 + ak);
        const float* bp = BpBase + (size_t)kt2 * N;
        #pragma unroll
        for (int i = 0; i < 16; i++) bp_[i] = bp[(size_t)i * N];
    };
    auto STORE = [&](const float4* ap, const float* bp_, short* As_, short* Bs_) {
        #pragma unroll
        for (int p = 0; p < 4; p++) {
            int m = (p << 4) + ar;
            uint2 wpk; wpk.x = pk2(ap[p].x, ap[p].y); wpk.y = pk2(ap[p].z, ap[p].w);
            *(uint2*)&As_[m * GST + ak] = wpk;
        }
        unsigned int u[8];
        #pragma unroll
        for (int i = 0; i < 8; i++) u[i] = pk2(bp_[2 * i], bp_[2 * i + 1]);
        *(uint4*)&Bs_[bn * GST + bkk]     = make_uint4(u[0], u[1], u[2], u[3]);
        *(uint4*)&Bs_[bn * GST + bkk + 8] = make_uint4(u[4], u[5], u[6], u[7]);
    };
    auto MM = [&](const short* As_, const short* Bs_) {
        #pragma unroll
        for (int ks = 0; ks < 2; ks++) {
            short8 af = *(const short8*)&As_[fm * GST + (ks << 5) + fk];
            #pragma unroll
            for (int nt = 0; nt < 4; nt++) {
                short8 bf = *(const short8*)&Bs_[((nt << 4) + fn) * GST + (ks << 5) + fk];
                acc[nt] = __builtin_amdgcn_mfma_f32_16x16x32_bf16(af, bf, acc[nt], 0, 0, 0);
            }
        }
    };

    // prologue: tile0 -> buf0; tile1 -> regsB
    LOAD(0, aA, bA);
    STORE(aA, bA, As[0], Bs[0]);
    LOAD(64, aB, bB);
    __syncthreads();

    for (int kt = 0; kt < K; kt += 128) {
        // EVEN tile (buf 0)
        if (kt + 128 < K) LOAD(kt + 128, aA, bA);
        MM(As[0], Bs[0]);
        STORE(aB, bB, As[1], Bs[1]);          // tile kt+64 -> buf1
        __syncthreads();
        // ODD tile (buf 1)
        if (kt + 192 < K) LOAD(kt + 192, aB, bB);
        MM(As[1], Bs[1]);
        if (kt + 128 < K) STORE(aA, bA, As[0], Bs[0]);
        __syncthreads();
    }

    int rowb = mbase + (wv << 4) + ((ln >> 4) << 2);
    if (mode == 2) {
        int tk[4];
        #pragma unroll
        for (int r = 0; r < 4; r++) tk[r] = perm[rowb + r];
        #pragma unroll
        for (int nt = 0; nt < 4; nt++) {
            int col = nbase + (nt << 4) + fn;
            float bsv = bias[biasoff + col];
            #pragma unroll
            for (int r = 0; r < 4; r++)
                if (tk[r] >= 0)
                    C[(size_t)tk[r] * N + col] = resf[(size_t)tk[r] * N + col] + acc[nt][r] + bsv;
        }
    } else {
        #pragma unroll
        for (int nt = 0; nt < 4; nt++) {
            int col = nbase + (nt << 4) + fn;
            float bsv = bias[col];
            #pragma unroll
            for (int r = 0; r < 4; r++) {
                float vv = acc[nt][r] + bsv;
                if (mode == 1) vv += resf[(size_t)(rowb + r) * N + col];
                C[(size_t)(rowb + r) * N + col] = vv;
            }
        }
    }
}

// ---------------- Fused Q/K/V projection (one dispatch), depth-2 pipeline --------
__global__ __launch_bounds__(256) void qkv_kernel(
    const float* __restrict__ A,
    const float* __restrict__ Wq, const float* __restrict__ bq,
    const float* __restrict__ Wk, const float* __restrict__ bk,
    const float* __restrict__ Wv, const float* __restrict__ bv,
    float* __restrict__ qo, float* __restrict__ ko, float* __restrict__ vo)
{
    __shared__ short As[2][64 * GST];
    __shared__ short Bs[2][64 * GST];
    int tid = threadIdx.x;
    int bx = blockIdx.x;
    int mbase = blockIdx.y * 64;

    const float* B; const float* bias; float* C; int N, nbase;
    if (bx < 16)      { B = Wq; bias = bq; C = qo; N = DIM;      nbase = bx * 64; }
    else if (bx < 20) { B = Wk; bias = bk; C = ko; N = NKV * HD; nbase = (bx - 16) * 64; }
    else              { B = Wv; bias = bv; C = vo; N = NKV * HD; nbase = (bx - 20) * 64; }

    int ar = tid >> 4, ak = (tid & 15) << 2;
    int bn = tid & 63, bkk = (tid >> 6) << 4;
    const float* BpBase = B + (size_t)bkk * N + nbase + bn;

    int wv = tid >> 6, ln = tid & 63;
    int fm = (wv << 4) + (ln & 15);
    int fn = ln & 15;
    int fk = (ln >> 4) << 3;

    floatx4 acc[4];
    #pragma unroll
    for (int nt = 0; nt < 4; nt++)
        #pragma unroll
        for (int r = 0; r < 4; r++) acc[nt][r] = 0.f;

    float4 aA[4], aB[4];
    float bA[16], bB[16];

    auto LOAD = [&](int kt2, float4* ap, float* bp_) {
        #pragma unroll
        for (int p = 0; p < 4; p++)
            ap[p] = *(const float4*)(A + (size_t)(mbase + (p << 4) + ar) * DIM + kt2 + ak);
        const float* bp = BpBase + (size_t)kt2 * N;
        #pragma unroll
        for (int i = 0; i < 16; i++) bp_[i] = bp[(size_t)i * N];
    };
    auto STORE = [&](const float4* ap, const float* bp_, short* As_, short* Bs_) {
        #pragma unroll
        for (int p = 0; p < 4; p++) {
            int m = (p << 4) + ar;
            uint2 wpk; wpk.x = pk2(ap[p].x, ap[p].y); wpk.y = pk2(ap[p].z, ap[p].w);
            *(uint2*)&As_[m * GST + ak] = wpk;
        }
        unsigned int u[8];
        #pragma unroll
        for (int i = 0; i < 8; i++) u[i] = pk2(bp_[2 * i], bp_[2 * i + 1]);
        *(uint4*)&Bs_[bn * GST + bkk]     = make_uint4(u[0], u[1], u[2], u[3]);
        *(uint4*)&Bs_[bn * GST + bkk + 8] = make_uint4(u[4], u[5], u[6], u[7]);
    };
    auto MM = [&](const short* As_, const short* Bs_) {
        #pragma unroll
        for (int ks = 0; ks < 2; ks++) {
            short8 af = *(const short8*)&As_[fm * GST + (ks << 5) + fk];
            #pragma unroll
            for (int nt = 0; nt < 4; nt++) {
                short8 bf = *(const short8*)&Bs_[((nt << 4) + fn) * GST + (ks << 5) + fk];
                acc[nt] = __builtin_amdgcn_mfma_f32_16x16x32_bf16(af, bf, acc[nt], 0, 0, 0);
            }
        }
    };

    LOAD(0, aA, bA);
    STORE(aA, bA, As[0], Bs[0]);
    LOAD(64, aB, bB);
    __syncthreads();

    for (int kt = 0; kt < DIM; kt += 128) {
        if (kt + 128 < DIM) LOAD(kt + 128, aA, bA);
        MM(As[0], Bs[0]);
        STORE(aB, bB, As[1], Bs[1]);
        __syncthreads();
        if (kt + 192 < DIM) LOAD(kt + 192, aB, bB);
        MM(As[1], Bs[1]);
        if (kt + 128 < DIM) STORE(aA, bA, As[0], Bs[0]);
        __syncthreads();
    }

    int rowb = mbase + (wv << 4) + ((ln >> 4) << 2);
    #pragma unroll
    for (int nt = 0; nt < 4; nt++) {
        int col = nbase + (nt << 4) + fn;
        float bsv = bias[col];
        #pragma unroll
        for (int r = 0; r < 4; r++)
            C[(size_t)(rowb + r) * N + col] = acc[nt][r] + bsv;
    }
}

// ---------------- Fused MoE up-proj + SwiGLU (64-row, dual-B, depth-2) ----------
__global__ __launch_bounds__(256) void moe1_kernel(
    const float* __restrict__ A,        // h2 [SEQ][DIM]
    const float* __restrict__ W1,       // [E][DIM][2*HID]
    const float* __restrict__ b1,       // [E][2*HID]
    float* __restrict__ act,            // [MAX_TILES*64][HID]
    const int* __restrict__ perm,
    const int* __restrict__ tile_expert)
{
    __shared__ short As[2][64 * GST];
    __shared__ short B1s[2][64 * GST];
    __shared__ short B2s[2][64 * GST];
    int tid = threadIdx.x;
    int mbase = blockIdx.y * 64, nbase = blockIdx.x * 64;
    int e = tile_expert[blockIdx.y];
    if (e < 0) return;
    const float* Wp = W1 + (size_t)e * DIM * (2 * HID);
    const float* bp1 = b1 + (size_t)e * (2 * HID);

    int ar = tid >> 4, ak = (tid & 15) << 2;
    int tok[4];
    #pragma unroll
    for (int p = 0; p < 4; p++) tok[p] = perm[mbase + (p << 4) + ar];

    int bn = tid & 63, bkk = (tid >> 6) << 4;
    const float* BpBase = Wp + (size_t)bkk * (2 * HID) + nbase + bn;

    int wv = tid >> 6, ln = tid & 63;
    int fm = (wv << 4) + (ln & 15);
    int fn = ln & 15;
    int fk = (ln >> 4) << 3;

    floatx4 acc1[4], acc2[4];
    #pragma unroll
    for (int nt = 0; nt < 4; nt++)
        #pragma unroll
        for (int r = 0; r < 4; r++) { acc1[nt][r] = 0.f; acc2[nt][r] = 0.f; }

    float4 aA[4], aB[4];
    float b1A[16], b1B[16], b2A[16], b2B[16];

    auto LOAD = [&](int kt2, float4* ap, float* b1p, float* b2p) {
        #pragma unroll
        for (int p = 0; p < 4; p++)
            ap[p] = (tok[p] >= 0)
                ? *(const float4*)(A + (size_t)tok[p] * DIM + kt2 + ak)
                : make_float4(0.f, 0.f, 0.f, 0.f);
        const float* bp = BpBase + (size_t)kt2 * (2 * HID);
        #pragma unroll
        for (int i = 0; i < 16; i++) {
            b1p[i] = bp[(size_t)i * (2 * HID)];
            b2p[i] = bp[(size_t)i * (2 * HID) + HID];
        }
    };
    auto STORE = [&](const float4* ap, const float* b1p, const float* b2p,
                     short* As_, short* B1s_, short* B2s_) {
        #pragma unroll
        for (int p = 0; p < 4; p++) {
            int m = (p << 4) + ar;
            uint2 wpk; wpk.x = pk2(ap[p].x, ap[p].y); wpk.y = pk2(ap[p].z, ap[p].w);
            *(uint2*)&As_[m * GST + ak] = wpk;
        }
        unsigned int u1[8], u2[8];
        #pragma unroll
        for (int i = 0; i < 8; i++) {
            u1[i] = pk2(b1p[2 * i], b1p[2 * i + 1]);
            u2[i] = pk2(b2p[2 * i], b2p[2 * i + 1]);
        }
        *(uint4*)&B1s_[bn * GST + bkk]     = make_uint4(u1[0], u1[1], u1[2], u1[3]);
        *(uint4*)&B1s_[bn * GST + bkk + 8] = make_uint4(u1[4], u1[5], u1[6], u1[7]);
        *(uint4*)&B2s_[bn * GST + bkk]     = make_uint4(u2[0], u2[1], u2[2], u2[3]);
        *(uint4*)&B2s_[bn * GST + bkk + 8] = make_uint4(u2[4], u2[5], u2[6], u2[7]);
    };
    auto MM = [&](const short* As_, const short* B1s_, const short* B2s_) {
        #pragma unroll
        for (int ks = 0; ks < 2; ks++) {
            short8 af = *(const short8*)&As_[fm * GST + (ks << 5) + fk];
            #pragma unroll
            for (int nt = 0; nt < 4; nt++) {
                int bo = ((nt << 4) + fn) * GST + (ks << 5) + fk;
                short8 bf1 = *(const short8*)&B1s_[bo];
                short8 bf2 = *(const short8*)&B2s_[bo];
                acc1[nt] = __builtin_amdgcn_mfma_f32_16x16x32_bf16(af, bf1, acc1[nt], 0, 0, 0);
                acc2[nt] = __builtin_amdgcn_mfma_f32_16x16x32_bf16(af, bf2, acc2[nt], 0, 0, 0);
            }
        }
    };

    LOAD(0, aA, b1A, b2A);
    STORE(aA, b1A, b2A, As[0], B1s[0], B2s[0]);
    LOAD(64, aB, b1B, b2B);
    __syncthreads();

    for (int kt = 0; kt < DIM; kt += 128) {
        if (kt + 128 < DIM) LOAD(kt + 128, aA, b1A, b2A);
        MM(As[0], B1s[0], B2s[0]);
        STORE(aB, b1B, b2B, As[1], B1s[1], B2s[1]);
        __syncthreads();
        if (kt + 192 < DIM) LOAD(kt + 192, aB, b1B, b2B);
        MM(As[1], B1s[1], B2s[1]);
        if (kt + 128 < DIM) STORE(aA, b1A, b2A, As[0], B1s[0], B2s[0]);
        __syncthreads();
    }

    int rowb = mbase + (wv << 4) + ((ln >> 4) << 2);
    #pragma unroll
    for (int nt = 0; nt < 4; nt++) {
        int col = nbase + (nt << 4) + fn;
        float bs1 = bp1[col];
        float bs2 = bp1[HID + col];
        #pragma unroll
        for (int r = 0; r < 4; r++) {
            float u1 = acc1[nt][r] + bs1;
            float u2 = acc2[nt][r] + bs2;
            act[(size_t)(rowb + r) * HID + col] = u1 * (1.0f / (1.0f + expf(-u2)));
        }
    }
}

// ---------------- RoPE + per-head RMSNorm (merged q/k dispatch) ----------------
__global__ __launch_bounds__(64) void rope_rms_kernel(float* __restrict__ qb,
                                                      float* __restrict__ kb,
                                                      const float* __restrict__ qnw,
                                                      const float* __restrict__ knw)
{
    int t = blockIdx.x, hy = blockIdx.y, d = threadIdx.x;
    float* x; const float* w; int nh, h;
    if (hy < NQ) { x = qb; w = qnw; nh = NQ;  h = hy; }
    else         { x = kb; w = knw; nh = NKV; h = hy - NQ; }
    int base = (t * nh + h) * HD;
    int i = d & 31;
    float x1 = x[base + i];
    float x2 = x[base + 32 + i];
    float inv = 1.0f / powf(10000.0f, (float)(2 * i) * (1.0f / HD));
    float fr = (float)t * inv;
    float c = cosf(fr), s = sinf(fr);
    float r = (d < 32) ? (x1 * c - x2 * s) : (x1 * s + x2 * c);
    float sq = r * r;
    #pragma unroll
    for (int m = 32; m >= 1; m >>= 1) sq += __shfl_xor(sq, m);
    float rs = 1.0f / sqrtf(sq * (1.0f / HD) + EPSF);
    __syncthreads();
    x[base + d] = r * rs * w[d];
}

// ---------------- MFMA flash attention (causal GQA) + fused sigmoid gate --------
__global__ __launch_bounds__(256) void fattn_kernel(const float* __restrict__ q,
                                                    const float* __restrict__ k,
                                                    const float* __restrict__ v,
                                                    const float* __restrict__ Wg,
                                                    const float* __restrict__ bg,
                                                    float* __restrict__ o)
{
    __shared__ short lds[2][2][64 * GST];   // [buf][0=K,1=V^T] ; 36864 B

    int h = blockIdx.x, qt = blockIdx.y;
    int kvh = h >> 2;
    int tid = threadIdx.x;
    int w = tid >> 6, ln = tid & 63;
    int c = ln & 15, g = ln >> 4;
    int qbase = qt * 64;
    const size_t krow = (size_t)NKV * HD;   // floats per token row in k/v

    short8 qf[2];
    {
        const float* qp = q + ((size_t)(qbase + 16 * w + c) * NQ + h) * HD + 8 * g;
        #pragma unroll
        for (int ks = 0; ks < 2; ks++) {
            float4 a = *(const float4*)(qp + 32 * ks);
            float4 b = *(const float4*)(qp + 32 * ks + 4);
            s8u t;
            t.u[0] = pk2(a.x * 0.125f, a.y * 0.125f);
            t.u[1] = pk2(a.z * 0.125f, a.w * 0.125f);
            t.u[2] = pk2(b.x * 0.125f, b.y * 0.125f);
            t.u[3] = pk2(b.z * 0.125f, b.w * 0.125f);
            qf[ks] = t.s;
        }
    }

    int kr[4], kd4[4];
    #pragma unroll
    for (int i = 0; i < 4; i++) { int f4 = tid + 256 * i; kr[i] = f4 >> 4; kd4[i] = f4 & 15; }
    int vd = tid & 63, vrb = (tid >> 6) << 4;

    float4 kreg[4];
    float vreg[16];
    {
        const float* kb = k + (size_t)kvh * HD;
        #pragma unroll
        for (int i = 0; i < 4; i++)
            kreg[i] = *(const float4*)(kb + (size_t)kr[i] * krow + kd4[i] * 4);
        const float* vb = v + (size_t)kvh * HD + vd;
        #pragma unroll
        for (int i = 0; i < 16; i++)
            vreg[i] = vb[(size_t)(vrb + i) * krow];
    }

    float m_i = -INFINITY, l_i = 0.f;
    floatx4 ot[4];
    #pragma unroll
    for (int mt = 0; mt < 4; mt++)
        #pragma unroll
        for (int r = 0; r < 4; r++) ot[mt][r] = 0.f;

    for (int kt = 0; kt <= qt; kt++) {
        short* KB = lds[kt & 1][0];
        short* VT = lds[kt & 1][1];

        #pragma unroll
        for (int i = 0; i < 4; i++) {
            uint2 wp; wp.x = pk2(kreg[i].x, kreg[i].y); wp.y = pk2(kreg[i].z, kreg[i].w);
            *(uint2*)&KB[kr[i] * GST + kd4[i] * 4] = wp;
        }
        {
            unsigned int u[8];
            #pragma unroll
            for (int i = 0; i < 8; i++) u[i] = pk2(vreg[2 * i], vreg[2 * i + 1]);
            *(uint4*)&VT[vd * GST + vrb]     = make_uint4(u[0], u[1], u[2], u[3]);
            *(uint4*)&VT[vd * GST + vrb + 8] = make_uint4(u[4], u[5], u[6], u[7]);
        }
        __syncthreads();

        if (kt < qt) {
            int kb2 = (kt + 1) * 64;
            const float* kb = k + ((size_t)kb2 * NKV + kvh) * HD;
            #pragma unroll
            for (int i = 0; i < 4; i++)
                kreg[i] = *(const float4*)(kb + (size_t)kr[i] * krow + kd4[i] * 4);
            const float* vp = v + ((size_t)kb2 * NKV + kvh) * HD + vd;
            #pragma unroll
            for (int i = 0; i < 16; i++)
                vreg[i] = vp[(size_t)(vrb + i) * krow];
        }

        float p[4][4];
        #pragma unroll
        for (int mt = 0; mt < 4; mt++) {
            floatx4 s = {0.f, 0.f, 0.f, 0.f};
            #pragma unroll
            for (int ks = 0; ks < 2; ks++) {
                short8 kf = *(const short8*)&KB[(16 * mt + c) * GST + 32 * ks + 8 * g];
                s = __builtin_amdgcn_mfma_f32_16x16x32_bf16(kf, qf[ks], s, 0, 0, 0);
            }
            #pragma unroll
            for (int r = 0; r < 4; r++) p[mt][r] = s[r];
        }

        if (kt == qt) {
            #pragma unroll
            for (int mt = 0; mt < 4; mt++)
                #pragma unroll
                for (int r = 0; r < 4; r++)
                    if (16 * mt + 4 * g + r > 16 * w + c) p[mt][r] = -1e30f;
        }

        float tm = p[0][0];
        #pragma unroll
        for (int mt = 0; mt < 4; mt++)
            #pragma unroll
            for (int r = 0; r < 4; r++) tm = fmaxf(tm, p[mt][r]);
        tm = fmaxf(tm, __shfl_xor(tm, 16));
        tm = fmaxf(tm, __shfl_xor(tm, 32));
        float mn = fmaxf(m_i, tm);
        float alpha = __expf(m_i - mn);
        float ts = 0.f;
        #pragma unroll
        for (int mt = 0; mt < 4; mt++)
            #pragma unroll
            for (int r = 0; r < 4; r++) {
                float e = __expf(p[mt][r] - mn);
                p[mt][r] = e; ts += e;
            }
        ts += __shfl_xor(ts, 16);
        ts += __shfl_xor(ts, 32);
        l_i = alpha * l_i + ts;
        m_i = mn;
        #pragma unroll
        for (int mt = 0; mt < 4; mt++)
            #pragma unroll
            for (int r = 0; r < 4; r++) ot[mt][r] *= alpha;

        unsigned int pd[4][2];
        #pragma unroll
        for (int mt = 0; mt < 4; mt++) {
            pd[mt][0] = pk2(p[mt][0], p[mt][1]);
            pd[mt][1] = pk2(p[mt][2], p[mt][3]);
        }

        int srcA = c + ((ln & 16) << 1);
        int srcB = srcA + 16;
        int gh = g >> 1;
        short8 pf[2];
        #pragma unroll
        for (int ks = 0; ks < 2; ks++) {
            s8u t;
            unsigned int a0 = (unsigned)__shfl((int)pd[2 * ks][0],     srcA);
            unsigned int a1 = (unsigned)__shfl((int)pd[2 * ks + 1][0], srcA);
            t.u[0] = gh ? a1 : a0;
            unsigned int b0 = (unsigned)__shfl((int)pd[2 * ks][1],     srcA);
            unsigned int b1 = (unsigned)__shfl((int)pd[2 * ks + 1][1], srcA);
            t.u[1] = gh ? b1 : b0;
            unsigned int c0 = (unsigned)__shfl((int)pd[2 * ks][0],     srcB);
            unsigned int c1 = (unsigned)__shfl((int)pd[2 * ks + 1][0], srcB);
            t.u[2] = gh ? c1 : c0;
            unsigned int d0 = (unsigned)__shfl((int)pd[2 * ks][1],     srcB);
            unsigned int d1 = (unsigned)__shfl((int)pd[2 * ks + 1][1], srcB);
            t.u[3] = gh ? d1 : d0;
            pf[ks] = t.s;
        }

        #pragma unroll
        for (int mt = 0; mt < 4; mt++) {
            #pragma unroll
            for (int ks = 0; ks < 2; ks++) {
                short8 vf = *(const short8*)&VT[(16 * mt + c) * GST + 32 * ks + 8 * g];
                ot[mt] = __builtin_amdgcn_mfma_f32_16x16x32_bf16(vf, pf[ks], ot[mt], 0, 0, 0);
            }
        }
    }

    // ---- epilogue: normalize -> OT LDS; stage Wg; fused f32 gate; store --------
    __syncthreads();
    float* L   = (float*)lds;          // OT [64][68] f32 = 17408 B
    float* WgS = L + 64 * 68;          // Wg [64][68] f32 = 17408 B (total 34816 B)

    int we = tid >> 2, wd = (tid & 3) << 4;
    float4 wg4[4];
    #pragma unroll
    for (int i = 0; i < 4; i++)
        wg4[i] = *(const float4*)(Wg + (size_t)we * HD + wd + 4 * i);

    float rl = 1.0f / l_i;
    #pragma unroll
    for (int mt = 0; mt < 4; mt++)
        #pragma unroll
        for (int r = 0; r < 4; r++)
            L[(16 * w + c) * 68 + 16 * mt + 4 * g + r] = ot[mt][r] * rl;
    #pragma unroll
    for (int i = 0; i < 4; i++)
        *(float4*)&WgS[we * 68 + wd + 4 * i] = wg4[i];
    __syncthreads();

    int r = tid >> 2, d0 = (tid & 3) << 4;
    float4 a0 = *(const float4*)(bg + d0);
    float4 a1 = *(const float4*)(bg + d0 + 4);
    float4 a2 = *(const float4*)(bg + d0 + 8);
    float4 a3 = *(const float4*)(bg + d0 + 12);
    for (int e = 0; e < HD; e++) {
        float ov = L[r * 68 + e];
        float4 w0 = *(const float4*)&WgS[e * 68 + d0];
        float4 w1 = *(const float4*)&WgS[e * 68 + d0 + 4];
        float4 w2 = *(const float4*)&WgS[e * 68 + d0 + 8];
        float4 w3 = *(const float4*)&WgS[e * 68 + d0 + 12];
        a0.x += ov * w0.x; a0.y += ov * w0.y; a0.z += ov * w0.z; a0.w += ov * w0.w;
        a1.x += ov * w1.x; a1.y += ov * w1.y; a1.z += ov * w1.z; a1.w += ov * w1.w;
        a2.x += ov * w2.x; a2.y += ov * w2.y; a2.z += ov * w2.z; a2.w += ov * w2.w;
        a3.x += ov * w3.x; a3.y += ov * w3.y; a3.z += ov * w3.z; a3.w += ov * w3.w;
    }
    float* op = o + ((size_t)(qbase + r) * NQ + h) * HD + d0;
    float4 av[4] = {a0, a1, a2, a3};
    #pragma unroll
    for (int i = 0; i < 4; i++) {
        float4 ov4 = *(const float4*)&L[r * 68 + d0 + 4 * i];
        float4 res;
        res.x = ov4.x / (1.0f + expf(-av[i].x));
        res.y = ov4.y / (1.0f + expf(-av[i].y));
        res.z = ov4.z / (1.0f + expf(-av[i].z));
        res.w = ov4.w / (1.0f + expf(-av[i].w));
        *(float4*)(op + 4 * i) = res;
    }
}

// ---------------- Router: logits + argmax (one wave per token) ----------------
__global__ __launch_bounds__(64) void router_kernel(const float* __restrict__ h2,
                                                    const float* __restrict__ Wr,
                                                    const float* __restrict__ br,
                                                    int* __restrict__ top1)
{
    int t = blockIdx.x, lane = threadIdx.x;
    float acc[NE] = {0.f, 0.f, 0.f, 0.f, 0.f, 0.f, 0.f, 0.f};
    for (int d = lane; d < DIM; d += 64) {
        float hv = h2[(size_t)t * DIM + d];
        float4 w0 = *(const float4*)(Wr + (size_t)d * NE);
        float4 w1 = *(const float4*)(Wr + (size_t)d * NE + 4);
        acc[0] += hv * w0.x; acc[1] += hv * w0.y;
        acc[2] += hv * w0.z; acc[3] += hv * w0.w;
        acc[4] += hv * w1.x; acc[5] += hv * w1.y;
        acc[6] += hv * w1.z; acc[7] += hv * w1.w;
    }
    #pragma unroll
    for (int e = 0; e < NE; e++)
        for (int off = 32; off >= 1; off >>= 1) acc[e] += __shfl_down(acc[e], off);
    if (lane == 0) {
        float best = acc[0] + br[0]; int be = 0;
        #pragma unroll
        for (int e = 1; e < NE; e++) {
            float l = acc[e] + br[e];
            if (l > best) { best = l; be = e; }   // strict > : first max wins (np.argmax)
        }
        top1[t] = be;
    }
}

// ---------------- Bucket tokens by expert into 64-padded tiles ----------------
__global__ __launch_bounds__(64) void bucket_kernel(const int* __restrict__ top1,
                                                    int* __restrict__ perm,
                                                    int* __restrict__ tile_expert)
{
    int lane = threadIdx.x;

    int e_of[16];
    {
        const int4* tp = (const int4*)(top1 + lane * 16);
        #pragma unroll
        for (int c = 0; c < 4; c++) {
            int4 v = tp[c];
            e_of[c * 4 + 0] = v.x & 7;
            e_of[c * 4 + 1] = v.y & 7;
            e_of[c * 4 + 2] = v.z & 7;
            e_of[c * 4 + 3] = v.w & 7;
        }
    }

    int cnt[NE];
    #pragma unroll
    for (int e = 0; e < NE; e++) {
        int c = 0;
        #pragma unroll
        for (int i = 0; i < 16; i++) c += (e_of[i] == e) ? 1 : 0;
        cnt[e] = c;
    }

    int pre[NE];
    #pragma unroll
    for (int e = 0; e < NE; e++) pre[e] = cnt[e];
    #pragma unroll
    for (int off = 1; off < 64; off <<= 1) {
        #pragma unroll
        for (int e = 0; e < NE; e++) {
            int t = __shfl_up(pre[e], off);
            if (lane >= off) pre[e] += t;
        }
    }
    int tot[NE];
    #pragma unroll
    for (int e = 0; e < NE; e++) {
        tot[e] = __shfl(pre[e], 63);
        pre[e] -= cnt[e];
    }

    int off_e[NE + 1];
    off_e[0] = 0;
    #pragma unroll
    for (int e = 0; e < NE; e++)
        off_e[e + 1] = off_e[e] + (((tot[e] + 63) >> 6) << 6);

    if (lane < MAX_TILES) {
        int tb = lane << 6;
        int te = -1;
        #pragma unroll
        for (int e = 0; e < NE; e++)
            if (tb >= off_e[e] && tb < off_e[e + 1]) te = e;
        tile_expert[lane] = te;
    }

    #pragma unroll
    for (int e = 0; e < NE; e++)
        for (int i = off_e[e] + tot[e] + lane; i < off_e[e + 1]; i += 64)
            perm[i] = -1;

    #pragma unroll
    for (int e = 0; e < NE; e++) {
        int pos = off_e[e] + pre[e];
        #pragma unroll
        for (int i = 0; i < 16; i++) {
            if (e_of[i] == e) { perm[pos] = lane * 16 + i; pos++; }
        }
    }
}

extern "C" void kernel_launch(void* const* d_in, const int* in_sizes, int n_in,
                              void* d_out, int out_size, void* d_ws, size_t ws_size,
                              hipStream_t stream)
{
    const float* x    = (const float*)d_in[0];
    const float* ln1w = (const float*)d_in[1];
    const float* ln2w = (const float*)d_in[2];
    const float* Wq   = (const float*)d_in[3];
    const float* bq   = (const float*)d_in[4];
    const float* Wk   = (const float*)d_in[5];
    const float* bk   = (const float*)d_in[6];
    const float* Wv   = (const float*)d_in[7];
    const float* bv   = (const float*)d_in[8];
    const float* qnw  = (const float*)d_in[9];
    const float* knw  = (const float*)d_in[10];
    const float* Wg   = (const float*)d_in[11];
    const float* bg   = (const float*)d_in[12];
    const float* Wo   = (const float*)d_in[13];
    const float* bo   = (const float*)d_in[14];
    const float* Wr   = (const float*)d_in[15];
    const float* br   = (const float*)d_in[16];
    const float* W1   = (const float*)d_in[17];
    const float* b1   = (const float*)d_in[18];
    const float* W2   = (const float*)d_in[19];
    const float* b2   = (const float*)d_in[20];
    float* out = (float*)d_out;
    (void)in_sizes; (void)n_in; (void)out_size; (void)ws_size;

    char* ws = (char*)d_ws;
    float* h    = (float*)(ws);
    float* q    = (float*)(ws + ((size_t)4  << 20));
    float* kbuf = (float*)(ws + ((size_t)8  << 20));
    float* vbuf = (float*)(ws + ((size_t)9  << 20));
    float* ao   = (float*)(ws + ((size_t)10 << 20));
    float* x2   = (float*)(ws);                          // over h (dead)
    float* h2   = (float*)(ws + ((size_t)4  << 20));     // over q (dead)
    float* act  = (float*)(ws + ((size_t)24 << 20));     // 12 MB: [24*64][HID]
    int* top1   = (int*)  (ws + ((size_t)44 << 20));
    int* perm   = top1 + 2048;
    int* texp   = perm + MAX_TILES * 64;

    rmsnorm_kernel<<<SEQ, 256, 0, stream>>>(x, ln1w, h);
    qkv_kernel<<<dim3(24, SEQ / 64), 256, 0, stream>>>(
        h, Wq, bq, Wk, bk, Wv, bv, q, kbuf, vbuf);
    rope_rms_kernel<<<dim3(SEQ, NQ + NKV), 64, 0, stream>>>(q, kbuf, qnw, knw);
    fattn_kernel<<<dim3(NQ, SEQ / 64), 256, 0, stream>>>(q, kbuf, vbuf, Wg, bg, ao);
    gemm_kernel<<<dim3(DIM / 64, SEQ / 64), 256, 0, stream>>>(
        ao, Wo, bo, x2, x, nullptr, nullptr, DIM, DIM, 1);
    rmsnorm_kernel<<<SEQ, 256, 0, stream>>>(x2, ln2w, h2);
    router_kernel<<<SEQ, 64, 0, stream>>>(h2, Wr, br, top1);
    bucket_kernel<<<1, 64, 0, stream>>>(top1, perm, texp);
    moe1_kernel<<<dim3(HID / 64, MAX_TILES), 256, 0, stream>>>(
        h2, W1, b1, act, perm, texp);
    gemm_kernel<<<dim3(DIM / 64, MAX_TILES), 256, 0, stream>>>(
        act, W2, b2, out, x2, perm, texp, DIM, HID, 2);
}

// Round 6
// 438.434 us; speedup vs baseline: 1.0330x; 1.0272x over previous
//
#include <hip/hip_runtime.h>
#include <hip/hip_bf16.h>
#include <cstddef>

#define DIM 1024
#define NQ 16
#define NKV 4
#define HD 64
#define HID 2048
#define NE 8
#define SEQ 1024
#define EPSF 1e-6f
#define MAX_TILES 24   // 64-row tiles: max sum of ceil(cnt_e/64): 1024/64 + 8 = 24
#define GST 72         // LDS k-stride in bf16 elems: 144 B, 16B-aligned rows

typedef __hip_bfloat16 bf16;
typedef __attribute__((ext_vector_type(8))) short short8;   // 8 bf16 = one MFMA A/B frag
typedef __attribute__((ext_vector_type(4))) float floatx4;  // MFMA C/D frag

typedef union { short8 s; unsigned int u[4]; } s8u;

__device__ __forceinline__ unsigned int f2b(float f) {
    union { bf16 b; unsigned short s; } u;
    u.b = __float2bfloat16(f);
    return (unsigned int)u.s;
}
__device__ __forceinline__ unsigned int pk2(float a, float b) {
    return f2b(a) | (f2b(b) << 16);
}

// ---------------- RMSNorm (row of 1024, f32 in/out) ----------------
__global__ __launch_bounds__(256) void rmsnorm_kernel(const float* __restrict__ src,
                                                      const float* __restrict__ w,
                                                      float* __restrict__ dst)
{
    int row = blockIdx.x, tid = threadIdx.x;
    __shared__ float red[256];
    float vals[4];
    float sq = 0.f;
    size_t base = (size_t)row * DIM;
    #pragma unroll
    for (int i = 0; i < 4; i++) {
        int idx = tid + i * 256;
        float v = src[base + idx];
        vals[i] = v; sq += v * v;
    }
    red[tid] = sq; __syncthreads();
    for (int s = 128; s > 0; s >>= 1) {
        if (tid < s) red[tid] += red[tid + s];
        __syncthreads();
    }
    float rs = 1.0f / sqrtf(red[0] * (1.0f / DIM) + EPSF);
    #pragma unroll
    for (int i = 0; i < 4; i++) {
        int idx = tid + i * 256;
        dst[base + idx] = w[idx] * vals[i] * rs;
    }
}

// ---------------- MFMA bf16 tiled GEMM (64 x NB tile, BK=64, 1-deep prefetch) ----
// R2-proven structure: STORE cur; bar; issue LOAD next; MFMA cur; bar.
// NB=32 doubles grid for latency-bound dispatches (TLP > per-block efficiency).
// mode 0: C = acc + bias ; mode 1: += resf[row] ; mode 2: perm-scatter + resf[tok]
template<int NB>
__global__ __launch_bounds__(256) void gemm_t(
    const float* __restrict__ A, const float* __restrict__ B, const float* __restrict__ bias,
    float* __restrict__ C, const float* __restrict__ resf,
    const int* __restrict__ perm, const int* __restrict__ tile_expert,
    int N, int K, int mode)
{
    constexpr int KR = NB / 4;            // k-rows staged per thread for B
    constexpr int NT = NB / 16;           // n-subtiles per block
    __shared__ short As[64 * GST];
    __shared__ short Bs[NB * GST];
    int tid = threadIdx.x;
    int mbase = blockIdx.y * 64, nbase = blockIdx.x * NB;

    size_t Beoff = 0, biasoff = 0;
    if (tile_expert) {
        int e = tile_expert[blockIdx.y];
        if (e < 0) return;
        Beoff = (size_t)e * K * N;
        biasoff = (size_t)e * N;
    }

    int ar = tid >> 4, ak = (tid & 15) << 2;
    int bn = tid & (NB - 1), bkk = (tid / NB) * KR;
    const float* BpBase = B + Beoff + (size_t)bkk * N + nbase + bn;

    int wv = tid >> 6, ln = tid & 63;
    int fm = (wv << 4) + (ln & 15);
    int fn = ln & 15;
    int fk = (ln >> 4) << 3;

    floatx4 acc[NT];
    #pragma unroll
    for (int nt = 0; nt < NT; nt++)
        #pragma unroll
        for (int r = 0; r < 4; r++) acc[nt][r] = 0.f;

    float4 apre[4];
    float bpre[KR];
    #pragma unroll
    for (int p = 0; p < 4; p++)
        apre[p] = *(const float4*)(A + (size_t)(mbase + (p << 4) + ar) * K + ak);
    #pragma unroll
    for (int i = 0; i < KR; i++)
        bpre[i] = BpBase[(size_t)i * N];

    for (int kt = 0; kt < K; kt += 64) {
        #pragma unroll
        for (int p = 0; p < 4; p++) {
            int m = (p << 4) + ar;
            uint2 wpk; wpk.x = pk2(apre[p].x, apre[p].y); wpk.y = pk2(apre[p].z, apre[p].w);
            *(uint2*)&As[m * GST + ak] = wpk;
        }
        #pragma unroll
        for (int i2 = 0; i2 < KR; i2 += 8) {
            unsigned int u[4];
            #pragma unroll
            for (int i = 0; i < 4; i++)
                u[i] = pk2(bpre[i2 + 2 * i], bpre[i2 + 2 * i + 1]);
            *(uint4*)&Bs[bn * GST + bkk + i2] = make_uint4(u[0], u[1], u[2], u[3]);
        }
        __syncthreads();

        int kn = kt + 64;
        if (kn < K) {   // issue next tile's loads; they land during MFMA below
            #pragma unroll
            for (int p = 0; p < 4; p++)
                apre[p] = *(const float4*)(A + (size_t)(mbase + (p << 4) + ar) * K + kn + ak);
            const float* bp = BpBase + (size_t)kn * N;
            #pragma unroll
            for (int i = 0; i < KR; i++) bpre[i] = bp[(size_t)i * N];
        }

        #pragma unroll
        for (int ks = 0; ks < 2; ks++) {
            short8 af = *(const short8*)&As[fm * GST + (ks << 5) + fk];
            #pragma unroll
            for (int nt = 0; nt < NT; nt++) {
                short8 bf = *(const short8*)&Bs[((nt << 4) + fn) * GST + (ks << 5) + fk];
                acc[nt] = __builtin_amdgcn_mfma_f32_16x16x32_bf16(af, bf, acc[nt], 0, 0, 0);
            }
        }
        __syncthreads();
    }

    int rowb = mbase + (wv << 4) + ((ln >> 4) << 2);
    if (mode == 2) {
        int tk[4];
        #pragma unroll
        for (int r = 0; r < 4; r++) tk[r] = perm[rowb + r];
        #pragma unroll
        for (int nt = 0; nt < NT; nt++) {
            int col = nbase + (nt << 4) + fn;
            float bsv = bias[biasoff + col];
            #pragma unroll
            for (int r = 0; r < 4; r++)
                if (tk[r] >= 0)
                    C[(size_t)tk[r] * N + col] = resf[(size_t)tk[r] * N + col] + acc[nt][r] + bsv;
        }
    } else {
        #pragma unroll
        for (int nt = 0; nt < NT; nt++) {
            int col = nbase + (nt << 4) + fn;
            float bsv = bias[col];
            #pragma unroll
            for (int r = 0; r < 4; r++) {
                float vv = acc[nt][r] + bsv;
                if (mode == 1) vv += resf[(size_t)(rowb + r) * N + col];
                C[(size_t)(rowb + r) * N + col] = vv;
            }
        }
    }
}

// ---------------- Fused Q/K/V projection (NB=32, 1-deep prefetch) ----------------
// blockIdx.x: [0,32) -> q (N=1024); [32,40) -> k; [40,48) -> v (N=256 each).
__global__ __launch_bounds__(256) void qkv_kernel(
    const float* __restrict__ A,
    const float* __restrict__ Wq, const float* __restrict__ bq,
    const float* __restrict__ Wk, const float* __restrict__ bk,
    const float* __restrict__ Wv, const float* __restrict__ bv,
    float* __restrict__ qo, float* __restrict__ ko, float* __restrict__ vo)
{
    constexpr int NB = 32, KR = 8, NT = 2;
    __shared__ short As[64 * GST];
    __shared__ short Bs[NB * GST];
    int tid = threadIdx.x;
    int bx = blockIdx.x;
    int mbase = blockIdx.y * 64;

    const float* B; const float* bias; float* C; int N, nbase;
    if (bx < 32)      { B = Wq; bias = bq; C = qo; N = DIM;      nbase = bx * 32; }
    else if (bx < 40) { B = Wk; bias = bk; C = ko; N = NKV * HD; nbase = (bx - 32) * 32; }
    else              { B = Wv; bias = bv; C = vo; N = NKV * HD; nbase = (bx - 40) * 32; }

    int ar = tid >> 4, ak = (tid & 15) << 2;
    int bn = tid & (NB - 1), bkk = (tid / NB) * KR;
    const float* BpBase = B + (size_t)bkk * N + nbase + bn;

    int wv = tid >> 6, ln = tid & 63;
    int fm = (wv << 4) + (ln & 15);
    int fn = ln & 15;
    int fk = (ln >> 4) << 3;

    floatx4 acc[NT];
    #pragma unroll
    for (int nt = 0; nt < NT; nt++)
        #pragma unroll
        for (int r = 0; r < 4; r++) acc[nt][r] = 0.f;

    float4 apre[4];
    float bpre[KR];
    #pragma unroll
    for (int p = 0; p < 4; p++)
        apre[p] = *(const float4*)(A + (size_t)(mbase + (p << 4) + ar) * DIM + ak);
    #pragma unroll
    for (int i = 0; i < KR; i++)
        bpre[i] = BpBase[(size_t)i * N];

    for (int kt = 0; kt < DIM; kt += 64) {
        #pragma unroll
        for (int p = 0; p < 4; p++) {
            int m = (p << 4) + ar;
            uint2 wpk; wpk.x = pk2(apre[p].x, apre[p].y); wpk.y = pk2(apre[p].z, apre[p].w);
            *(uint2*)&As[m * GST + ak] = wpk;
        }
        {
            unsigned int u[4];
            #pragma unroll
            for (int i = 0; i < 4; i++)
                u[i] = pk2(bpre[2 * i], bpre[2 * i + 1]);
            *(uint4*)&Bs[bn * GST + bkk] = make_uint4(u[0], u[1], u[2], u[3]);
        }
        __syncthreads();

        int kn = kt + 64;
        if (kn < DIM) {
            #pragma unroll
            for (int p = 0; p < 4; p++)
                apre[p] = *(const float4*)(A + (size_t)(mbase + (p << 4) + ar) * DIM + kn + ak);
            const float* bp = BpBase + (size_t)kn * N;
            #pragma unroll
            for (int i = 0; i < KR; i++) bpre[i] = bp[(size_t)i * N];
        }

        #pragma unroll
        for (int ks = 0; ks < 2; ks++) {
            short8 af = *(const short8*)&As[fm * GST + (ks << 5) + fk];
            #pragma unroll
            for (int nt = 0; nt < NT; nt++) {
                short8 bf = *(const short8*)&Bs[((nt << 4) + fn) * GST + (ks << 5) + fk];
                acc[nt] = __builtin_amdgcn_mfma_f32_16x16x32_bf16(af, bf, acc[nt], 0, 0, 0);
            }
        }
        __syncthreads();
    }

    int rowb = mbase + (wv << 4) + ((ln >> 4) << 2);
    #pragma unroll
    for (int nt = 0; nt < NT; nt++) {
        int col = nbase + (nt << 4) + fn;
        float bsv = bias[col];
        #pragma unroll
        for (int r = 0; r < 4; r++)
            C[(size_t)(rowb + r) * N + col] = acc[nt][r] + bsv;
    }
}

// ---------------- Fused MoE up-proj + SwiGLU (64x32 tile, dual-B, 1-deep) --------
__global__ __launch_bounds__(256) void moe1_kernel(
    const float* __restrict__ A,        // h2 [SEQ][DIM]
    const float* __restrict__ W1,       // [E][DIM][2*HID]
    const float* __restrict__ b1,       // [E][2*HID]
    float* __restrict__ act,            // [MAX_TILES*64][HID]
    const int* __restrict__ perm,
    const int* __restrict__ tile_expert)
{
    constexpr int NB = 32, KR = 8, NT = 2;
    __shared__ short As[64 * GST];
    __shared__ short B1s[NB * GST];
    __shared__ short B2s[NB * GST];
    int tid = threadIdx.x;
    int mbase = blockIdx.y * 64, nbase = blockIdx.x * NB;
    int e = tile_expert[blockIdx.y];
    if (e < 0) return;
    const float* Wp = W1 + (size_t)e * DIM * (2 * HID);
    const float* bp1 = b1 + (size_t)e * (2 * HID);

    int ar = tid >> 4, ak = (tid & 15) << 2;
    int tok[4];
    #pragma unroll
    for (int p = 0; p < 4; p++) tok[p] = perm[mbase + (p << 4) + ar];

    int bn = tid & (NB - 1), bkk = (tid / NB) * KR;
    const float* BpBase = Wp + (size_t)bkk * (2 * HID) + nbase + bn;

    int wv = tid >> 6, ln = tid & 63;
    int fm = (wv << 4) + (ln & 15);
    int fn = ln & 15;
    int fk = (ln >> 4) << 3;

    floatx4 acc1[NT], acc2[NT];
    #pragma unroll
    for (int nt = 0; nt < NT; nt++)
        #pragma unroll
        for (int r = 0; r < 4; r++) { acc1[nt][r] = 0.f; acc2[nt][r] = 0.f; }

    float4 apre[4];
    float b1pre[KR], b2pre[KR];
    #pragma unroll
    for (int p = 0; p < 4; p++)
        apre[p] = (tok[p] >= 0)
            ? *(const float4*)(A + (size_t)tok[p] * DIM + ak)
            : make_float4(0.f, 0.f, 0.f, 0.f);
    #pragma unroll
    for (int i = 0; i < KR; i++) {
        b1pre[i] = BpBase[(size_t)i * (2 * HID)];
        b2pre[i] = BpBase[(size_t)i * (2 * HID) + HID];
    }

    for (int kt = 0; kt < DIM; kt += 64) {
        #pragma unroll
        for (int p = 0; p < 4; p++) {
            int m = (p << 4) + ar;
            uint2 wpk; wpk.x = pk2(apre[p].x, apre[p].y); wpk.y = pk2(apre[p].z, apre[p].w);
            *(uint2*)&As[m * GST + ak] = wpk;
        }
        {
            unsigned int u1[4], u2[4];
            #pragma unroll
            for (int i = 0; i < 4; i++) {
                u1[i] = pk2(b1pre[2 * i], b1pre[2 * i + 1]);
                u2[i] = pk2(b2pre[2 * i], b2pre[2 * i + 1]);
            }
            *(uint4*)&B1s[bn * GST + bkk] = make_uint4(u1[0], u1[1], u1[2], u1[3]);
            *(uint4*)&B2s[bn * GST + bkk] = make_uint4(u2[0], u2[1], u2[2], u2[3]);
        }
        __syncthreads();

        int kn = kt + 64;
        if (kn < DIM) {   // issue next tile's loads; land during dual-MFMA below
            #pragma unroll
            for (int p = 0; p < 4; p++)
                apre[p] = (tok[p] >= 0)
                    ? *(const float4*)(A + (size_t)tok[p] * DIM + kn + ak)
                    : make_float4(0.f, 0.f, 0.f, 0.f);
            const float* bp = BpBase + (size_t)kn * (2 * HID);
            #pragma unroll
            for (int i = 0; i < KR; i++) {
                b1pre[i] = bp[(size_t)i * (2 * HID)];
                b2pre[i] = bp[(size_t)i * (2 * HID) + HID];
            }
        }

        #pragma unroll
        for (int ks = 0; ks < 2; ks++) {
            short8 af = *(const short8*)&As[fm * GST + (ks << 5) + fk];
            #pragma unroll
            for (int nt = 0; nt < NT; nt++) {
                int bo = ((nt << 4) + fn) * GST + (ks << 5) + fk;
                short8 bf1 = *(const short8*)&B1s[bo];
                short8 bf2 = *(const short8*)&B2s[bo];
                acc1[nt] = __builtin_amdgcn_mfma_f32_16x16x32_bf16(af, bf1, acc1[nt], 0, 0, 0);
                acc2[nt] = __builtin_amdgcn_mfma_f32_16x16x32_bf16(af, bf2, acc2[nt], 0, 0, 0);
            }
        }
        __syncthreads();
    }

    int rowb = mbase + (wv << 4) + ((ln >> 4) << 2);
    #pragma unroll
    for (int nt = 0; nt < NT; nt++) {
        int col = nbase + (nt << 4) + fn;
        float bs1 = bp1[col];
        float bs2 = bp1[HID + col];
        #pragma unroll
        for (int r = 0; r < 4; r++) {
            float u1 = acc1[nt][r] + bs1;
            float u2 = acc2[nt][r] + bs2;
            act[(size_t)(rowb + r) * HID + col] = u1 * (1.0f / (1.0f + expf(-u2)));
        }
    }
}

// ---------------- RoPE + per-head RMSNorm (merged q/k dispatch) ----------------
__global__ __launch_bounds__(64) void rope_rms_kernel(float* __restrict__ qb,
                                                      float* __restrict__ kb,
                                                      const float* __restrict__ qnw,
                                                      const float* __restrict__ knw)
{
    int t = blockIdx.x, hy = blockIdx.y, d = threadIdx.x;
    float* x; const float* w; int nh, h;
    if (hy < NQ) { x = qb; w = qnw; nh = NQ;  h = hy; }
    else         { x = kb; w = knw; nh = NKV; h = hy - NQ; }
    int base = (t * nh + h) * HD;
    int i = d & 31;
    float x1 = x[base + i];
    float x2 = x[base + 32 + i];
    float inv = 1.0f / powf(10000.0f, (float)(2 * i) * (1.0f / HD));
    float fr = (float)t * inv;
    float c = cosf(fr), s = sinf(fr);
    float r = (d < 32) ? (x1 * c - x2 * s) : (x1 * s + x2 * c);
    float sq = r * r;
    #pragma unroll
    for (int m = 32; m >= 1; m >>= 1) sq += __shfl_xor(sq, m);
    float rs = 1.0f / sqrtf(sq * (1.0f / HD) + EPSF);
    __syncthreads();
    x[base + d] = r * rs * w[d];
}

// ---------------- MFMA flash attention (causal GQA) + fused sigmoid gate --------
__global__ __launch_bounds__(256) void fattn_kernel(const float* __restrict__ q,
                                                    const float* __restrict__ k,
                                                    const float* __restrict__ v,
                                                    const float* __restrict__ Wg,
                                                    const float* __restrict__ bg,
                                                    float* __restrict__ o)
{
    __shared__ short lds[2][2][64 * GST];   // [buf][0=K,1=V^T] ; 36864 B

    int h = blockIdx.x, qt = blockIdx.y;
    int kvh = h >> 2;
    int tid = threadIdx.x;
    int w = tid >> 6, ln = tid & 63;
    int c = ln & 15, g = ln >> 4;
    int qbase = qt * 64;
    const size_t krow = (size_t)NKV * HD;   // floats per token row in k/v

    short8 qf[2];
    {
        const float* qp = q + ((size_t)(qbase + 16 * w + c) * NQ + h) * HD + 8 * g;
        #pragma unroll
        for (int ks = 0; ks < 2; ks++) {
            float4 a = *(const float4*)(qp + 32 * ks);
            float4 b = *(const float4*)(qp + 32 * ks + 4);
            s8u t;
            t.u[0] = pk2(a.x * 0.125f, a.y * 0.125f);
            t.u[1] = pk2(a.z * 0.125f, a.w * 0.125f);
            t.u[2] = pk2(b.x * 0.125f, b.y * 0.125f);
            t.u[3] = pk2(b.z * 0.125f, b.w * 0.125f);
            qf[ks] = t.s;
        }
    }

    int kr[4], kd4[4];
    #pragma unroll
    for (int i = 0; i < 4; i++) { int f4 = tid + 256 * i; kr[i] = f4 >> 4; kd4[i] = f4 & 15; }
    int vd = tid & 63, vrb = (tid >> 6) << 4;

    float4 kreg[4];
    float vreg[16];
    {
        const float* kb = k + (size_t)kvh * HD;
        #pragma unroll
        for (int i = 0; i < 4; i++)
            kreg[i] = *(const float4*)(kb + (size_t)kr[i] * krow + kd4[i] * 4);
        const float* vb = v + (size_t)kvh * HD + vd;
        #pragma unroll
        for (int i = 0; i < 16; i++)
            vreg[i] = vb[(size_t)(vrb + i) * krow];
    }

    float m_i = -INFINITY, l_i = 0.f;
    floatx4 ot[4];
    #pragma unroll
    for (int mt = 0; mt < 4; mt++)
        #pragma unroll
        for (int r = 0; r < 4; r++) ot[mt][r] = 0.f;

    for (int kt = 0; kt <= qt; kt++) {
        short* KB = lds[kt & 1][0];
        short* VT = lds[kt & 1][1];

        #pragma unroll
        for (int i = 0; i < 4; i++) {
            uint2 wp; wp.x = pk2(kreg[i].x, kreg[i].y); wp.y = pk2(kreg[i].z, kreg[i].w);
            *(uint2*)&KB[kr[i] * GST + kd4[i] * 4] = wp;
        }
        {
            unsigned int u[8];
            #pragma unroll
            for (int i = 0; i < 8; i++) u[i] = pk2(vreg[2 * i], vreg[2 * i + 1]);
            *(uint4*)&VT[vd * GST + vrb]     = make_uint4(u[0], u[1], u[2], u[3]);
            *(uint4*)&VT[vd * GST + vrb + 8] = make_uint4(u[4], u[5], u[6], u[7]);
        }
        __syncthreads();

        if (kt < qt) {
            int kb2 = (kt + 1) * 64;
            const float* kb = k + ((size_t)kb2 * NKV + kvh) * HD;
            #pragma unroll
            for (int i = 0; i < 4; i++)
                kreg[i] = *(const float4*)(kb + (size_t)kr[i] * krow + kd4[i] * 4);
            const float* vp = v + ((size_t)kb2 * NKV + kvh) * HD + vd;
            #pragma unroll
            for (int i = 0; i < 16; i++)
                vreg[i] = vp[(size_t)(vrb + i) * krow];
        }

        float p[4][4];
        #pragma unroll
        for (int mt = 0; mt < 4; mt++) {
            floatx4 s = {0.f, 0.f, 0.f, 0.f};
            #pragma unroll
            for (int ks = 0; ks < 2; ks++) {
                short8 kf = *(const short8*)&KB[(16 * mt + c) * GST + 32 * ks + 8 * g];
                s = __builtin_amdgcn_mfma_f32_16x16x32_bf16(kf, qf[ks], s, 0, 0, 0);
            }
            #pragma unroll
            for (int r = 0; r < 4; r++) p[mt][r] = s[r];
        }

        if (kt == qt) {
            #pragma unroll
            for (int mt = 0; mt < 4; mt++)
                #pragma unroll
                for (int r = 0; r < 4; r++)
                    if (16 * mt + 4 * g + r > 16 * w + c) p[mt][r] = -1e30f;
        }

        float tm = p[0][0];
        #pragma unroll
        for (int mt = 0; mt < 4; mt++)
            #pragma unroll
            for (int r = 0; r < 4; r++) tm = fmaxf(tm, p[mt][r]);
        tm = fmaxf(tm, __shfl_xor(tm, 16));
        tm = fmaxf(tm, __shfl_xor(tm, 32));
        float mn = fmaxf(m_i, tm);
        float alpha = __expf(m_i - mn);
        float ts = 0.f;
        #pragma unroll
        for (int mt = 0; mt < 4; mt++)
            #pragma unroll
            for (int r = 0; r < 4; r++) {
                float e = __expf(p[mt][r] - mn);
                p[mt][r] = e; ts += e;
            }
        ts += __shfl_xor(ts, 16);
        ts += __shfl_xor(ts, 32);
        l_i = alpha * l_i + ts;
        m_i = mn;
        #pragma unroll
        for (int mt = 0; mt < 4; mt++)
            #pragma unroll
            for (int r = 0; r < 4; r++) ot[mt][r] *= alpha;

        unsigned int pd[4][2];
        #pragma unroll
        for (int mt = 0; mt < 4; mt++) {
            pd[mt][0] = pk2(p[mt][0], p[mt][1]);
            pd[mt][1] = pk2(p[mt][2], p[mt][3]);
        }

        int srcA = c + ((ln & 16) << 1);
        int srcB = srcA + 16;
        int gh = g >> 1;
        short8 pf[2];
        #pragma unroll
        for (int ks = 0; ks < 2; ks++) {
            s8u t;
            unsigned int a0 = (unsigned)__shfl((int)pd[2 * ks][0],     srcA);
            unsigned int a1 = (unsigned)__shfl((int)pd[2 * ks + 1][0], srcA);
            t.u[0] = gh ? a1 : a0;
            unsigned int b0 = (unsigned)__shfl((int)pd[2 * ks][1],     srcA);
            unsigned int b1 = (unsigned)__shfl((int)pd[2 * ks + 1][1], srcA);
            t.u[1] = gh ? b1 : b0;
            unsigned int c0 = (unsigned)__shfl((int)pd[2 * ks][0],     srcB);
            unsigned int c1 = (unsigned)__shfl((int)pd[2 * ks + 1][0], srcB);
            t.u[2] = gh ? c1 : c0;
            unsigned int d0 = (unsigned)__shfl((int)pd[2 * ks][1],     srcB);
            unsigned int d1 = (unsigned)__shfl((int)pd[2 * ks + 1][1], srcB);
            t.u[3] = gh ? d1 : d0;
            pf[ks] = t.s;
        }

        #pragma unroll
        for (int mt = 0; mt < 4; mt++) {
            #pragma unroll
            for (int ks = 0; ks < 2; ks++) {
                short8 vf = *(const short8*)&VT[(16 * mt + c) * GST + 32 * ks + 8 * g];
                ot[mt] = __builtin_amdgcn_mfma_f32_16x16x32_bf16(vf, pf[ks], ot[mt], 0, 0, 0);
            }
        }
    }

    // ---- epilogue: normalize -> OT LDS; stage Wg; fused f32 gate; store --------
    __syncthreads();
    float* L   = (float*)lds;          // OT [64][68] f32 = 17408 B
    float* WgS = L + 64 * 68;          // Wg [64][68] f32 = 17408 B (total 34816 B)

    int we = tid >> 2, wd = (tid & 3) << 4;
    float4 wg4[4];
    #pragma unroll
    for (int i = 0; i < 4; i++)
        wg4[i] = *(const float4*)(Wg + (size_t)we * HD + wd + 4 * i);

    float rl = 1.0f / l_i;
    #pragma unroll
    for (int mt = 0; mt < 4; mt++)
        #pragma unroll
        for (int r = 0; r < 4; r++)
            L[(16 * w + c) * 68 + 16 * mt + 4 * g + r] = ot[mt][r] * rl;
    #pragma unroll
    for (int i = 0; i < 4; i++)
        *(float4*)&WgS[we * 68 + wd + 4 * i] = wg4[i];
    __syncthreads();

    int r = tid >> 2, d0 = (tid & 3) << 4;
    float4 a0 = *(const float4*)(bg + d0);
    float4 a1 = *(const float4*)(bg + d0 + 4);
    float4 a2 = *(const float4*)(bg + d0 + 8);
    float4 a3 = *(const float4*)(bg + d0 + 12);
    for (int e = 0; e < HD; e++) {
        float ov = L[r * 68 + e];
        float4 w0 = *(const float4*)&WgS[e * 68 + d0];
        float4 w1 = *(const float4*)&WgS[e * 68 + d0 + 4];
        float4 w2 = *(const float4*)&WgS[e * 68 + d0 + 8];
        float4 w3 = *(const float4*)&WgS[e * 68 + d0 + 12];
        a0.x += ov * w0.x; a0.y += ov * w0.y; a0.z += ov * w0.z; a0.w += ov * w0.w;
        a1.x += ov * w1.x; a1.y += ov * w1.y; a1.z += ov * w1.z; a1.w += ov * w1.w;
        a2.x += ov * w2.x; a2.y += ov * w2.y; a2.z += ov * w2.z; a2.w += ov * w2.w;
        a3.x += ov * w3.x; a3.y += ov * w3.y; a3.z += ov * w3.z; a3.w += ov * w3.w;
    }
    float* op = o + ((size_t)(qbase + r) * NQ + h) * HD + d0;
    float4 av[4] = {a0, a1, a2, a3};
    #pragma unroll
    for (int i = 0; i < 4; i++) {
        float4 ov4 = *(const float4*)&L[r * 68 + d0 + 4 * i];
        float4 res;
        res.x = ov4.x / (1.0f + expf(-av[i].x));
        res.y = ov4.y / (1.0f + expf(-av[i].y));
        res.z = ov4.z / (1.0f + expf(-av[i].z));
        res.w = ov4.w / (1.0f + expf(-av[i].w));
        *(float4*)(op + 4 * i) = res;
    }
}

// ---------------- Router: logits + argmax (one wave per token) ----------------
__global__ __launch_bounds__(64) void router_kernel(const float* __restrict__ h2,
                                                    const float* __restrict__ Wr,
                                                    const float* __restrict__ br,
                                                    int* __restrict__ top1)
{
    int t = blockIdx.x, lane = threadIdx.x;
    float acc[NE] = {0.f, 0.f, 0.f, 0.f, 0.f, 0.f, 0.f, 0.f};
    for (int d = lane; d < DIM; d += 64) {
        float hv = h2[(size_t)t * DIM + d];
        float4 w0 = *(const float4*)(Wr + (size_t)d * NE);
        float4 w1 = *(const float4*)(Wr + (size_t)d * NE + 4);
        acc[0] += hv * w0.x; acc[1] += hv * w0.y;
        acc[2] += hv * w0.z; acc[3] += hv * w0.w;
        acc[4] += hv * w1.x; acc[5] += hv * w1.y;
        acc[6] += hv * w1.z; acc[7] += hv * w1.w;
    }
    #pragma unroll
    for (int e = 0; e < NE; e++)
        for (int off = 32; off >= 1; off >>= 1) acc[e] += __shfl_down(acc[e], off);
    if (lane == 0) {
        float best = acc[0] + br[0]; int be = 0;
        #pragma unroll
        for (int e = 1; e < NE; e++) {
            float l = acc[e] + br[e];
            if (l > best) { best = l; be = e; }   // strict > : first max wins (np.argmax)
        }
        top1[t] = be;
    }
}

// ---------------- Bucket tokens by expert into 64-padded tiles ----------------
__global__ __launch_bounds__(64) void bucket_kernel(const int* __restrict__ top1,
                                                    int* __restrict__ perm,
                                                    int* __restrict__ tile_expert)
{
    int lane = threadIdx.x;

    int e_of[16];
    {
        const int4* tp = (const int4*)(top1 + lane * 16);
        #pragma unroll
        for (int c = 0; c < 4; c++) {
            int4 v = tp[c];
            e_of[c * 4 + 0] = v.x & 7;
            e_of[c * 4 + 1] = v.y & 7;
            e_of[c * 4 + 2] = v.z & 7;
            e_of[c * 4 + 3] = v.w & 7;
        }
    }

    int cnt[NE];
    #pragma unroll
    for (int e = 0; e < NE; e++) {
        int c = 0;
        #pragma unroll
        for (int i = 0; i < 16; i++) c += (e_of[i] == e) ? 1 : 0;
        cnt[e] = c;
    }

    int pre[NE];
    #pragma unroll
    for (int e = 0; e < NE; e++) pre[e] = cnt[e];
    #pragma unroll
    for (int off = 1; off < 64; off <<= 1) {
        #pragma unroll
        for (int e = 0; e < NE; e++) {
            int t = __shfl_up(pre[e], off);
            if (lane >= off) pre[e] += t;
        }
    }
    int tot[NE];
    #pragma unroll
    for (int e = 0; e < NE; e++) {
        tot[e] = __shfl(pre[e], 63);
        pre[e] -= cnt[e];
    }

    int off_e[NE + 1];
    off_e[0] = 0;
    #pragma unroll
    for (int e = 0; e < NE; e++)
        off_e[e + 1] = off_e[e] + (((tot[e] + 63) >> 6) << 6);

    if (lane < MAX_TILES) {
        int tb = lane << 6;
        int te = -1;
        #pragma unroll
        for (int e = 0; e < NE; e++)
            if (tb >= off_e[e] && tb < off_e[e + 1]) te = e;
        tile_expert[lane] = te;
    }

    #pragma unroll
    for (int e = 0; e < NE; e++)
        for (int i = off_e[e] + tot[e] + lane; i < off_e[e + 1]; i += 64)
            perm[i] = -1;

    #pragma unroll
    for (int e = 0; e < NE; e++) {
        int pos = off_e[e] + pre[e];
        #pragma unroll
        for (int i = 0; i < 16; i++) {
            if (e_of[i] == e) { perm[pos] = lane * 16 + i; pos++; }
        }
    }
}

extern "C" void kernel_launch(void* const* d_in, const int* in_sizes, int n_in,
                              void* d_out, int out_size, void* d_ws, size_t ws_size,
                              hipStream_t stream)
{
    const float* x    = (const float*)d_in[0];
    const float* ln1w = (const float*)d_in[1];
    const float* ln2w = (const float*)d_in[2];
    const float* Wq   = (const float*)d_in[3];
    const float* bq   = (const float*)d_in[4];
    const float* Wk   = (const float*)d_in[5];
    const float* bk   = (const float*)d_in[6];
    const float* Wv   = (const float*)d_in[7];
    const float* bv   = (const float*)d_in[8];
    const float* qnw  = (const float*)d_in[9];
    const float* knw  = (const float*)d_in[10];
    const float* Wg   = (const float*)d_in[11];
    const float* bg   = (const float*)d_in[12];
    const float* Wo   = (const float*)d_in[13];
    const float* bo   = (const float*)d_in[14];
    const float* Wr   = (const float*)d_in[15];
    const float* br   = (const float*)d_in[16];
    const float* W1   = (const float*)d_in[17];
    const float* b1   = (const float*)d_in[18];
    const float* W2   = (const float*)d_in[19];
    const float* b2   = (const float*)d_in[20];
    float* out = (float*)d_out;
    (void)in_sizes; (void)n_in; (void)out_size; (void)ws_size;

    char* ws = (char*)d_ws;
    float* h    = (float*)(ws);
    float* q    = (float*)(ws + ((size_t)4  << 20));
    float* kbuf = (float*)(ws + ((size_t)8  << 20));
    float* vbuf = (float*)(ws + ((size_t)9  << 20));
    float* ao   = (float*)(ws + ((size_t)10 << 20));
    float* x2   = (float*)(ws);                          // over h (dead)
    float* h2   = (float*)(ws + ((size_t)4  << 20));     // over q (dead)
    float* act  = (float*)(ws + ((size_t)24 << 20));     // 12 MB: [24*64][HID]
    int* top1   = (int*)  (ws + ((size_t)44 << 20));
    int* perm   = top1 + 2048;
    int* texp   = perm + MAX_TILES * 64;

    rmsnorm_kernel<<<SEQ, 256, 0, stream>>>(x, ln1w, h);
    qkv_kernel<<<dim3(48, SEQ / 64), 256, 0, stream>>>(
        h, Wq, bq, Wk, bk, Wv, bv, q, kbuf, vbuf);
    rope_rms_kernel<<<dim3(SEQ, NQ + NKV), 64, 0, stream>>>(q, kbuf, qnw, knw);
    fattn_kernel<<<dim3(NQ, SEQ / 64), 256, 0, stream>>>(q, kbuf, vbuf, Wg, bg, ao);
    gemm_t<32><<<dim3(DIM / 32, SEQ / 64), 256, 0, stream>>>(
        ao, Wo, bo, x2, x, nullptr, nullptr, DIM, DIM, 1);
    rmsnorm_kernel<<<SEQ, 256, 0, stream>>>(x2, ln2w, h2);
    router_kernel<<<SEQ, 64, 0, stream>>>(h2, Wr, br, top1);
    bucket_kernel<<<1, 64, 0, stream>>>(top1, perm, texp);
    moe1_kernel<<<dim3(HID / 32, MAX_TILES), 256, 0, stream>>>(
        h2, W1, b1, act, perm, texp);
    gemm_t<32><<<dim3(DIM / 32, MAX_TILES), 256, 0, stream>>>(
        act, W2, b2, out, x2, perm, texp, DIM, HID, 2);
}